// Round 9
// baseline (1086.075 us; speedup 1.0000x reference)
//
#include <hip/hip_runtime.h>
#include <math.h>

typedef unsigned short u16;
typedef short bf16x8 __attribute__((ext_vector_type(8)));
typedef float f32x4 __attribute__((ext_vector_type(4)));

// Shapes: B=2, N=96, H=768, H2=384, P=128, HEADS=12, D=64, T=17, CIN=3200
// PAIRS = 18432 ; tril pairs = 9120

// ---------------- workspace layout (floats, after 4KB header) ------------------
static constexpr size_t O_MULTI  = 0;                       // (192,1536)
static constexpr size_t O_XWF    = O_MULTI + 294912;        // (192,1152)
static constexpr size_t O_XWB    = O_XWF   + 221184;
static constexpr size_t O_HBUF   = O_XWB   + 221184;
static constexpr size_t O_CONST  = O_HBUF  + 3072;          // (18432,128)
static constexpr size_t O_STRUCT = O_CONST + 2359296;       // (18432,128)
static constexpr size_t O_PATHS  = O_STRUCT+ 2359296;       // l1/b1 bf16 (9.4MB)
static constexpr size_t O_NODES  = O_PATHS + 2359296;
static constexpr size_t O_QB     = O_NODES + 147456;
static constexpr size_t O_KB     = O_QB    + 147456;
static constexpr size_t O_VB     = O_KB    + 147456;
static constexpr size_t O_SKB    = O_VB    + 147456;        // (18432,64)
static constexpr size_t O_SVB    = O_SKB   + 1179648;
static constexpr size_t O_ATT    = O_SVB   + 1179648;
static constexpr size_t O_NP     = O_ATT   + 147456;        // 6 x (192,128)
static constexpr size_t O_LAL    = O_NP    + 147456;
static constexpr size_t O_LBL    = O_LAL   + 147456;
static constexpr size_t O_LAB    = O_LBL   + 147456;
static constexpr size_t O_LBB    = O_LAB   + 147456;
static constexpr size_t O_END    = O_LBB   + 147456;        // 11652096 floats

// bf16 weight region WBF (u16 units), placed after O_END
static constexpr int B_QW  = 0;          // 768x768
static constexpr int B_KW  = 589824;
static constexpr int B_VW  = 1179648;
static constexpr int B_OW  = 1769472;
static constexpr int B_IHF = 2359296;    // 1152x768
static constexpr int B_IHB = 3244032;
static constexpr int B_RA  = 4128768;    // 128x768 (wr cols 0:768)
static constexpr int B_RB  = 4227072;    // wr cols 768:1536
static constexpr int B_ZA  = 4325376;
static constexpr int B_ZB  = 4423680;
static constexpr int B_CA  = 4521984;    // wc cols 0:768
static constexpr int B_CB  = 4620288;
static constexpr int B_CBF = 4718592;    // 262144: wsk|wsv|wrs|wzs|wu|w1l|w1b
static constexpr int B_MBF = 4980736;    // multibf (192,1536)
static constexpr int B_NBF = 5275648;    // nodesbf (192,768)
static constexpr int B_ABF = 5423104;    // attoutbf (192,768)
static constexpr int CVT_TOT = 4980736;  // converted by cvt_weights

// offsets inside CBF (relative)
static constexpr int C_WSK = 0;
static constexpr int C_WSV = 8192;
static constexpr int C_WRS = 16384;
static constexpr int C_WZS = 32768;
static constexpr int C_WU  = 49152;
static constexpr int C_W1L = 65536;
static constexpr int C_W1B = 163840;

__device__ __forceinline__ u16 f2bf(float f) {
  union { float f; unsigned u; } v; v.f = f;
  unsigned r = v.u + 0x7fff + ((v.u >> 16) & 1);
  return (u16)(r >> 16);
}

// ---------------- init: dialog_input into multi (+bf16); zero flags ------------
__global__ void init_kernel(const float* __restrict__ sentences,
                            const float* __restrict__ root,
                            float* __restrict__ multi, u16* __restrict__ multibf,
                            int* bar) {
  int idx = blockIdx.x * 256 + threadIdx.x;
  if (idx < 12) bar[idx * 64] = 0;
  if (idx >= 2 * 96 * 768) return;
  int c = idx % 768;
  int rem = idx / 768;
  int t = rem % 96;
  int b = rem / 96;
  float v = (t == 0) ? root[c] : sentences[((size_t)(b * 95 + (t - 1))) * 768 + c];
  size_t a = ((size_t)(b * 96 + t)) * 1536 + c;
  multi[a] = v;
  multibf[a] = f2bf(v);
}

// ---------------- const_path + struct_path init --------------------------------
__global__ void init_pairs_kernel(const int* __restrict__ speakers,
                                  const int* __restrict__ turns,
                                  const int* __restrict__ graphs,
                                  const float* __restrict__ emb_speaker,
                                  const float* __restrict__ emb_turn,
                                  const float* __restrict__ emb_position,
                                  const float* __restrict__ normal_type,
                                  float* __restrict__ cpath,
                                  float* __restrict__ spath) {
  int idx = blockIdx.x * 256 + threadIdx.x;
  if (idx >= 18432 * 128) return;
  int c = idx & 127;
  int p = idx >> 7;
  int j = p % 96;
  int rem = p / 96;
  int i = rem % 96;
  int b = rem / 96;
  float cv;
  if (c < 32) {
    cv = emb_speaker[speakers[p] * 32 + c];
  } else if (c < 64) {
    cv = emb_turn[turns[p] * 32 + (c - 32)];
  } else {
    int d = j - i;
    d = min(max(d, -11), 11) + 11;
    cv = emb_position[d * 64 + (c - 64)];
  }
  cpath[idx] = cv;
  int g2 = graphs[p] + graphs[(b * 96 + j) * 96 + i];
  spath[idx] = (g2 == 0) ? 0.f : normal_type[(g2 - 1) * 128 + c];
}

// ---------------- convert all persistent weights to bf16 -----------------------
__global__ void cvt_weights_kernel(const float* __restrict__ wq, const float* __restrict__ wk,
                                   const float* __restrict__ wv, const float* __restrict__ wo,
                                   const float* __restrict__ wih_f, const float* __restrict__ wih_b,
                                   const float* __restrict__ wr, const float* __restrict__ wz,
                                   const float* __restrict__ wc, const float* __restrict__ wsk,
                                   const float* __restrict__ wsv, const float* __restrict__ wu,
                                   const float* __restrict__ link_w1, const float* __restrict__ lab_w1,
                                   u16* __restrict__ wbf) {
  int idx = blockIdx.x * 256 + threadIdx.x;
  if (idx >= CVT_TOT) return;
  float v;
  if (idx < B_IHF) {
    int which = idx / 589824, r = idx % 589824;
    const float* src = which == 0 ? wq : which == 1 ? wk : which == 2 ? wv : wo;
    v = src[r];
  } else if (idx < B_RA) {
    int r = idx - B_IHF;
    v = (r < 884736) ? wih_f[r] : wih_b[r - 884736];
  } else if (idx < B_CBF) {
    int r = idx - B_RA;
    int seg = r / 98304, q = r % 98304;
    int row = q / 768, c = q % 768;
    switch (seg) {
      case 0: v = wr[(size_t)row * 1664 + c]; break;
      case 1: v = wr[(size_t)row * 1664 + 768 + c]; break;
      case 2: v = wz[(size_t)row * 1664 + c]; break;
      case 3: v = wz[(size_t)row * 1664 + 768 + c]; break;
      case 4: v = wc[(size_t)row * 1536 + c]; break;
      default: v = wc[(size_t)row * 1536 + 768 + c]; break;
    }
  } else {
    int r = idx - B_CBF;
    if (r < C_WSV) v = wsk[r];
    else if (r < C_WRS) v = wsv[r - C_WSV];
    else if (r < C_WZS) { int q = r - C_WRS; v = wr[(size_t)(q >> 7) * 1664 + 1536 + (q & 127)]; }
    else if (r < C_WU)  { int q = r - C_WZS; v = wz[(size_t)(q >> 7) * 1664 + 1536 + (q & 127)]; }
    else if (r < C_W1L) v = wu[r - C_WU];
    else if (r < C_W1B) { int q = r - C_W1L; v = link_w1[(size_t)(q >> 7) * 3200 + 3072 + (q & 127)]; }
    else { int q = r - C_W1B; v = lab_w1[(size_t)(q >> 7) * 3200 + 3072 + (q & 127)]; }
  }
  wbf[idx] = f2bf(v);
}

// ---------------- generic MFMA GEMM: C = A(bf16) @ W(bf16)^T (+bias) -----------
struct BJob { const u16* W; const float* bias; float* C; };
struct BJobs { BJob j[6]; };

__global__ __launch_bounds__(256) void bgemm_kernel(const u16* __restrict__ A,
                                                    int lda, int K, int N, BJobs jobs) {
  BJob jb = jobs.j[blockIdx.z];
  int r0 = blockIdx.x * 16;
  int tid = threadIdx.x;
  int wave = tid >> 6, lane = tid & 63;
  int col = lane & 15, quad = lane >> 4;
  int c = blockIdx.y * 64 + wave * 16 + col;
  const u16* arow = A + (size_t)(r0 + col) * lda + quad * 8;
  const u16* brow = jb.W + (size_t)c * K + quad * 8;
  f32x4 acc = {0.f, 0.f, 0.f, 0.f};
  for (int k = 0; k < K; k += 32) {
    bf16x8 af = *(const bf16x8*)(arow + k);
    bf16x8 bf = *(const bf16x8*)(brow + k);
    acc = __builtin_amdgcn_mfma_f32_16x16x32_bf16(af, bf, acc, 0, 0, 0);
  }
  float bv = jb.bias ? jb.bias[c] : 0.f;
#pragma unroll
  for (int r = 0; r < 4; ++r)
    jb.C[(size_t)(r0 + quad * 4 + r) * N + c] = acc[r] + bv;
}

// ------- fused symmetrize + LN(struct+const) + sk/sv MFMA (64 pairs/block) -----
// 512 threads. Phase 1: 8 waves x 8 pairs LN -> bf16 in LDS (stride 136).
// Phase 2: wave = mat(2) x rowgrp(4); K=128 MFMA against wsk/wsv.
__device__ __forceinline__ void lnsksv_body(int blk, int tid,
                                            float* __restrict__ spath,
                                            const float* __restrict__ cpath,
                                            const float* __restrict__ pln_s,
                                            const float* __restrict__ pln_b,
                                            const u16* __restrict__ cbf,
                                            const float* __restrict__ bsk,
                                            const float* __restrict__ bsv,
                                            float* __restrict__ skb,
                                            float* __restrict__ svb,
                                            int store_upper, u16* plds) {
  int p0 = blk * 64;
  int wave = tid >> 6, lane = tid & 63;
  float pls0 = pln_s[lane], pls1 = pln_s[lane + 64];
  float plb0 = pln_b[lane], plb1 = pln_b[lane + 64];
#pragma unroll
  for (int pp = 0; pp < 8; ++pp) {
    int pl = wave * 8 + pp;
    int p = p0 + pl;
    int j = p % 96;
    int rem = p / 96;
    int i = rem % 96;
    int b = rem / 96;
    size_t self = (size_t)p * 128;
    const float* src = (i < j) ? (spath + ((size_t)((b * 96 + j) * 96 + i)) * 128)
                               : (spath + self);
    float v0 = src[lane], v1 = src[lane + 64];
    if (store_upper && i < j) {
      spath[self + lane] = v0;
      spath[self + lane + 64] = v1;
    }
    float x0 = v0 + cpath[self + lane];
    float x1 = v1 + cpath[self + lane + 64];
    float s = x0 + x1;
    for (int off = 32; off; off >>= 1) s += __shfl_xor(s, off, 64);
    float mean = s * (1.f / 128.f);
    float d0 = x0 - mean, d1 = x1 - mean;
    float vs = d0 * d0 + d1 * d1;
    for (int off = 32; off; off >>= 1) vs += __shfl_xor(vs, off, 64);
    float rstd = rsqrtf(vs * (1.f / 128.f) + 1e-5f);
    plds[pl * 136 + lane] = f2bf(d0 * rstd * pls0 + plb0);
    plds[pl * 136 + lane + 64] = f2bf(d1 * rstd * pls1 + plb1);
  }
  __syncthreads();
  int mat = wave >> 2, rowg = wave & 3;
  const u16* wb = cbf + (mat ? C_WSV : C_WSK);
  const float* bias = mat ? bsv : bsk;
  float* out = mat ? svb : skb;
  int col = lane & 15, quad = lane >> 4;
  bf16x8 afrag[4];
  const u16* arow = plds + (rowg * 16 + col) * 136 + quad * 8;
#pragma unroll
  for (int c = 0; c < 4; ++c) afrag[c] = *(const bf16x8*)(arow + 32 * c);
#pragma unroll
  for (int nt = 0; nt < 4; ++nt) {
    f32x4 acc = {0.f, 0.f, 0.f, 0.f};
    const u16* brow = wb + (size_t)(nt * 16 + col) * 128 + quad * 8;
#pragma unroll
    for (int c = 0; c < 4; ++c)
      acc = __builtin_amdgcn_mfma_f32_16x16x32_bf16(afrag[c], *(const bf16x8*)(brow + 32 * c), acc, 0, 0, 0);
    int o = nt * 16 + col;
    float bv = bias[o];
#pragma unroll
    for (int r = 0; r < 4; ++r)
      out[(size_t)(p0 + rowg * 16 + quad * 4 + r) * 64 + o] = acc[r] + bv;
  }
}

__global__ __launch_bounds__(512) void lnsksv_kernel(float* __restrict__ spath,
                                                     const float* __restrict__ cpath,
                                                     const float* __restrict__ pln_s,
                                                     const float* __restrict__ pln_b,
                                                     const u16* __restrict__ cbf,
                                                     const float* __restrict__ bsk,
                                                     const float* __restrict__ bsv,
                                                     float* __restrict__ skb,
                                                     float* __restrict__ svb,
                                                     int store_upper) {
  __shared__ u16 plds[64 * 136];
  lnsksv_body(blockIdx.x, threadIdx.x, spath, cpath, pln_s, pln_b, cbf, bsk, bsv,
              skb, svb, store_upper, plds);
}

// ---------------- mega kernel: gru (12 blocks) + hidden helpers ----------------
// bx<12: bi-GRU scan (unchanged protocol from R7: relaxed agent atomics,
// vmcnt(0) release, no L2 flush fences). 12<=bx<300: fused lnsksv layer 0.
// bx>=300: link/lab W1 main-slice bf16 conversion (grid-stride, 84 blocks).
__global__ __launch_bounds__(512) void mega_gru_kernel(
    const float* __restrict__ whh_f, const float* __restrict__ whh_b,
    const float* __restrict__ bhh_f, const float* __restrict__ bhh_b,
    const float* __restrict__ xwf, const float* __restrict__ xwb,
    float* hbuf, float* multi, u16* multibf, int* bar,
    float* __restrict__ spath, const float* __restrict__ cpath,
    const float* __restrict__ pln_s, const float* __restrict__ pln_b,
    const u16* __restrict__ cbf, const float* __restrict__ bsk,
    const float* __restrict__ bsv, float* __restrict__ skb,
    float* __restrict__ svb, const float* __restrict__ link_w1,
    const float* __restrict__ lab_w1, u16* __restrict__ l1, u16* __restrict__ b1) {
  __shared__ float hlds[768];
  __shared__ float part[3][64][2][17];
  __shared__ u16 plds[64 * 136];
  int bx = blockIdx.x;
  int tid = threadIdx.x;

  if (bx >= 300) {  // W1 conversion helpers
    for (int idx = (bx - 300) * 512 + tid; idx < 2359296; idx += 84 * 512) {
      int half = idx / 1179648;
      int r = idx % 1179648;
      int row = r / 1536, c = r % 1536;
      size_t src = (size_t)row * 3200 + half * 1536 + c;
      l1[idx] = f2bf(link_w1[src]);
      b1[idx] = f2bf(lab_w1[src]);
    }
    return;
  }
  if (bx >= 12) {  // layer-0 lnsksv helpers
    lnsksv_body(bx - 12, tid, spath, cpath, pln_s, pln_b, cbf, bsk, bsv, skb, svb,
                0, plds);
    return;
  }

  // ---- gru role ----
  int dir = bx / 6;
  int sub = bx % 6;
  const float* whh = dir ? whh_b : whh_f;
  const float* bhh = dir ? bhh_b : bhh_f;
  const float* xw = dir ? xwb : xwf;
  float* hb = hbuf + (size_t)dir * 1536;
  int* flags = bar + dir * 6 * 64;

  int ks = tid >> 5;
  int ug = tid & 31;
  int hv0 = ug * 2;

  float4 wreg[6][6];
#pragma unroll
  for (int d = 0; d < 2; ++d)
#pragma unroll
    for (int g = 0; g < 3; ++g) {
      const float* wrow = whh + (size_t)(g * 384 + sub * 64 + hv0 + d) * 384 + ks * 24;
#pragma unroll
      for (int m = 0; m < 6; ++m) wreg[d * 3 + g][m] = *(const float4*)(wrow + m * 4);
    }
  float bh0 = 0.f, bh1 = 0.f, bh2 = 0.f;
  int hvC = 0, bsel = 0;
  if (tid < 128) {
    hvC = sub * 64 + (tid >> 1);
    bsel = tid & 1;
    bh0 = bhh[hvC];
    bh1 = bhh[384 + hvC];
    bh2 = bhh[768 + hvC];
  }

  for (int s = 0; s < 96; ++s) {
    int t = dir ? (95 - s) : s;
    float xr = 0.f, xz = 0.f, xn = 0.f;
    if (tid < 128) {
      const float* xrow = xw + (size_t)(bsel * 96 + t) * 1152;
      xr = xrow[hvC]; xz = xrow[384 + hvC]; xn = xrow[768 + hvC];
    }
    if (s == 0) {
      __syncthreads();
      for (int k = tid; k < 768; k += 512) hlds[k] = 0.f;
    } else {
      if (tid < 6) {
        while (__hip_atomic_load(&flags[tid * 64], __ATOMIC_RELAXED,
                                 __HIP_MEMORY_SCOPE_AGENT) < s)
          __builtin_amdgcn_s_sleep(1);
      }
      __syncthreads();
      const float* hsrc = hb + ((s - 1) & 1) * 768;
      for (int k = tid; k < 768; k += 512)
        hlds[k] = __hip_atomic_load(&hsrc[k], __ATOMIC_RELAXED, __HIP_MEMORY_SCOPE_AGENT);
    }
    __syncthreads();

    float acc[6][2];
#pragma unroll
    for (int b = 0; b < 2; ++b) {
      float4 h4[6];
      const float* hp = hlds + b * 384 + ks * 24;
#pragma unroll
      for (int m = 0; m < 6; ++m) h4[m] = *(const float4*)(hp + m * 4);
#pragma unroll
      for (int u = 0; u < 6; ++u) {
        float ssum = 0.f;
#pragma unroll
        for (int m = 0; m < 6; ++m) {
          float4 w = wreg[u][m];
          ssum += w.x * h4[m].x + w.y * h4[m].y + w.z * h4[m].z + w.w * h4[m].w;
        }
        acc[u][b] = ssum;
      }
    }
#pragma unroll
    for (int d = 0; d < 2; ++d)
#pragma unroll
      for (int g = 0; g < 3; ++g) {
        part[g][hv0 + d][0][ks] = acc[d * 3 + g][0];
        part[g][hv0 + d][1][ks] = acc[d * 3 + g][1];
      }
    __syncthreads();

    float hn = 0.f;
    if (tid < 128) {
      int hv = tid >> 1;
      float gr = bh0, gz = bh1, gn = bh2;
#pragma unroll
      for (int q = 0; q < 16; ++q) {
        gr += part[0][hv][bsel][q];
        gz += part[1][hv][bsel][q];
        gn += part[2][hv][bsel][q];
      }
      float r = 1.f / (1.f + expf(-(xr + gr)));
      float z = 1.f / (1.f + expf(-(xz + gz)));
      float n = tanhf(xn + r * gn);
      float hp = hlds[bsel * 384 + hvC];
      hn = (1.f - z) * n + z * hp;
      __hip_atomic_store(&hb[(s & 1) * 768 + bsel * 384 + hvC], hn, __ATOMIC_RELAXED,
                         __HIP_MEMORY_SCOPE_AGENT);
    }
    asm volatile("s_waitcnt vmcnt(0)" ::: "memory");
    __syncthreads();
    if (tid == 0)
      __hip_atomic_store(&flags[sub * 64], s + 1, __ATOMIC_RELAXED,
                         __HIP_MEMORY_SCOPE_AGENT);
    if (tid < 128) {
      size_t a = ((size_t)(bsel * 96 + t)) * 1536 + 768 + dir * 384 + hvC;
      multi[a] = hn;
      multibf[a] = f2bf(hn);
    }
  }
}

// ---------------- fused attention per (b,i), bf16 output ------------------------
__global__ __launch_bounds__(256) void attn_kernel(const float* __restrict__ qb,
                                                   const float* __restrict__ kb,
                                                   const float* __restrict__ vb,
                                                   const float* __restrict__ skb,
                                                   const float* __restrict__ svb,
                                                   const int* __restrict__ edu_nums,
                                                   u16* __restrict__ attout) {
  int bi = blockIdx.x;
  int b = bi / 96;
  __shared__ float qrow[768];
  __shared__ float sc[12][100];
  int tid = threadIdx.x;
  for (int k = tid; k < 768; k += 256) qrow[k] = qb[(size_t)bi * 768 + k];
  int edun = edu_nums[b];
  __syncthreads();
  for (int task = tid; task < 12 * 96; task += 256) {
    int h = task / 96, j = task % 96;
    const float* krow = kb + ((size_t)(b * 96 + j)) * 768 + h * 64;
    const float* skrow = skb + ((size_t)(bi * 96 + j)) * 64;
    float s = 0.f;
    for (int d4 = 0; d4 < 64; d4 += 4) {
      float4 qv = *(const float4*)(qrow + h * 64 + d4);
      float4 kv = *(const float4*)(krow + d4);
      float4 sv = *(const float4*)(skrow + d4);
      s += qv.x * (kv.x + sv.x) + qv.y * (kv.y + sv.y) + qv.z * (kv.z + sv.z) +
           qv.w * (kv.w + sv.w);
    }
    s *= 0.125f;
    if (j >= edun) s -= 1e9f;
    sc[h][j] = s;
  }
  __syncthreads();
  if (tid < 12) {
    int h = tid;
    float m = -3.4e38f;
    for (int j = 0; j < 96; ++j) m = fmaxf(m, sc[h][j]);
    float sum = 0.f;
    for (int j = 0; j < 96; ++j) {
      float e = expf(sc[h][j] - m);
      sc[h][j] = e;
      sum += e;
    }
    float r = 1.f / sum;
    for (int j = 0; j < 96; ++j) sc[h][j] *= r;
  }
  __syncthreads();
  for (int o = tid; o < 768; o += 256) {
    int h = o >> 6, d = o & 63;
    float acc = 0.f;
    const float* vcol = vb + (size_t)(b * 96) * 768 + o;
    const float* svcol = svb + ((size_t)(bi * 96)) * 64 + d;
    for (int j = 0; j < 96; ++j) acc += sc[h][j] * (vcol[j * 768] + svcol[j * 64]);
    attout[(size_t)bi * 768 + o] = f2bf(acc);
  }
}

// ------- fused attn-out projection + nodes = LN(src + relu(proj)) --------------
// grid 12 x 256: block handles 16 rows x all 768 cols (MFMA), then row-LN.
__global__ __launch_bounds__(256) void oln_kernel(const u16* __restrict__ attoutbf,
                                                  const u16* __restrict__ wo_bf,
                                                  const float* __restrict__ bo,
                                                  const float* __restrict__ src,
                                                  int lda,
                                                  const float* __restrict__ ln_s,
                                                  const float* __restrict__ ln_b,
                                                  float* __restrict__ nodes,
                                                  u16* __restrict__ nodesbf) {
  __shared__ float buf[16][772];
  int r0 = blockIdx.x * 16;
  int tid = threadIdx.x;
  int wave = tid >> 6, lane = tid & 63;
  int col = lane & 15, quad = lane >> 4;

  bf16x8 af[24];
  const u16* arow = attoutbf + (size_t)(r0 + col) * 768 + quad * 8;
#pragma unroll
  for (int c = 0; c < 24; ++c) af[c] = *(const bf16x8*)(arow + 32 * c);

  for (int nt = wave; nt < 48; nt += 4) {
    int o0 = nt * 16;
    f32x4 acc = {0.f, 0.f, 0.f, 0.f};
    const u16* brow = wo_bf + (size_t)(o0 + col) * 768 + quad * 8;
#pragma unroll
    for (int c = 0; c < 24; ++c)
      acc = __builtin_amdgcn_mfma_f32_16x16x32_bf16(af[c], *(const bf16x8*)(brow + 32 * c), acc, 0, 0, 0);
    int o = o0 + col;
    float bv = bo[o];
#pragma unroll
    for (int r = 0; r < 4; ++r) {
      int row = quad * 4 + r;
      buf[row][o] = src[(size_t)(r0 + row) * lda + o] + fmaxf(acc[r] + bv, 0.f);
    }
  }
  __syncthreads();

#pragma unroll
  for (int rr = 0; rr < 4; ++rr) {
    int row = wave * 4 + rr;
    float x[12];
    float s = 0.f;
#pragma unroll
    for (int m = 0; m < 12; ++m) {
      x[m] = buf[row][lane + m * 64];
      s += x[m];
    }
    for (int off = 32; off; off >>= 1) s += __shfl_xor(s, off, 64);
    float mean = s * (1.f / 768.f);
    float vs = 0.f;
#pragma unroll
    for (int m = 0; m < 12; ++m) {
      float d = x[m] - mean;
      x[m] = d;
      vs += d * d;
    }
    for (int off = 32; off; off >>= 1) vs += __shfl_xor(vs, off, 64);
    float rstd = rsqrtf(vs * (1.f / 768.f) + 1e-5f);
#pragma unroll
    for (int m = 0; m < 12; ++m) {
      int e = lane + m * 64;
      float v = x[m] * rstd * ln_s[e] + ln_b[e];
      nodes[(size_t)(r0 + row) * 768 + e] = v;
      nodesbf[(size_t)(r0 + row) * 768 + e] = f2bf(v);
    }
  }
}

// ---------------- pairwise gate update via MFMA (tril pairs) --------------------
__global__ __launch_bounds__(256) void gate_mfma_kernel(float* __restrict__ spath,
                                                        const float* __restrict__ np,
                                                        const u16* __restrict__ cbf,
                                                        const float* __restrict__ br,
                                                        const float* __restrict__ bz,
                                                        const float* __restrict__ bc,
                                                        const float* __restrict__ bu) {
  __shared__ int addrs[16], npi[16], npj[16];
  int tid = threadIdx.x;
  if (tid < 16) {
    int pid = blockIdx.x * 16 + tid;
    int b = pid / 4560;
    int t = pid % 4560;
    int i = (int)((sqrtf(8.f * (float)t + 1.f) + 1.f) * 0.5f);
    while (i * (i - 1) / 2 > t) --i;
    while ((i + 1) * i / 2 <= t) ++i;
    int j = t - i * (i - 1) / 2;
    addrs[tid] = ((b * 96 + i) * 96 + j) * 128;
    npi[tid] = (b * 96 + i) * 128;
    npj[tid] = (b * 96 + j) * 128;
  }
  __syncthreads();

  int wave = tid >> 6, lane = tid & 63;
  int col = lane & 15, quad = lane >> 4;

  bf16x8 afrag[4];
  {
    const float* arow = spath + (size_t)addrs[col] + quad * 8;
#pragma unroll
    for (int c = 0; c < 4; ++c) {
      bf16x8 f;
#pragma unroll
      for (int q = 0; q < 8; ++q) f[q] = (short)f2bf(arow[32 * c + q]);
      afrag[c] = f;
    }
  }

  const u16* wrs = cbf + C_WRS;
  const u16* wzs = cbf + C_WZS;
  const u16* wu = cbf + C_WU;

  f32x4 cr[2], cz[2], cu[2];
#pragma unroll
  for (int ct = 0; ct < 2; ++ct) {
    cr[ct] = {0.f, 0.f, 0.f, 0.f};
    cz[ct] = {0.f, 0.f, 0.f, 0.f};
    cu[ct] = {0.f, 0.f, 0.f, 0.f};
    int o0 = wave * 32 + ct * 16;
    const u16* br_ = wrs + (size_t)(o0 + col) * 128 + quad * 8;
    const u16* bz_ = wzs + (size_t)(o0 + col) * 128 + quad * 8;
    const u16* bu_ = wu + (size_t)(o0 + col) * 128 + quad * 8;
#pragma unroll
    for (int c = 0; c < 4; ++c) {
      cr[ct] = __builtin_amdgcn_mfma_f32_16x16x32_bf16(afrag[c], *(const bf16x8*)(br_ + 32 * c), cr[ct], 0, 0, 0);
      cz[ct] = __builtin_amdgcn_mfma_f32_16x16x32_bf16(afrag[c], *(const bf16x8*)(bz_ + 32 * c), cz[ct], 0, 0, 0);
      cu[ct] = __builtin_amdgcn_mfma_f32_16x16x32_bf16(afrag[c], *(const bf16x8*)(bu_ + 32 * c), cu[ct], 0, 0, 0);
    }
  }

#pragma unroll
  for (int ct = 0; ct < 2; ++ct) {
    int o = wave * 32 + ct * 16 + col;
    float brv = br[o], bzv = bz[o], bcv = bc[o], buv = bu[o];
#pragma unroll
    for (int r4 = 0; r4 < 4; ++r4) {
      int m = quad * 4 + r4;
      int sa = addrs[m] + o;
      float so = spath[sa];
      float nra = np[0 * 24576 + npj[m] + o];
      float nrb = np[1 * 24576 + npi[m] + o];
      float nza = np[2 * 24576 + npj[m] + o];
      float nzb = np[3 * 24576 + npi[m] + o];
      float nca = np[4 * 24576 + npj[m] + o];
      float ncb = np[5 * 24576 + npi[m] + o];
      float r = 1.f / (1.f + expf(-(cr[ct][r4] + nra + nrb + brv)));
      float z = 1.f / (1.f + expf(-(cz[ct][r4] + nza + nzb + bzv)));
      float u = tanhf(nca + ncb + bcv + r * (cu[ct][r4] + buv));
      spath[sa] = z * so + (1.f - z) * u;
    }
  }
}

// ---------------- final fused link/label head (MFMA, converts spath inline) ----
__global__ __launch_bounds__(256) void final_mfma_kernel(
    const float* __restrict__ spath, const u16* __restrict__ cbf,
    const float* __restrict__ LAl, const float* __restrict__ LBl,
    const float* __restrict__ LAb, const float* __restrict__ LBb,
    const float* __restrict__ w2l, const float* __restrict__ w2b,
    const float* __restrict__ b2l, const float* __restrict__ b2b,
    float* __restrict__ outlink, float* __restrict__ outlab) {
  const u16* w1l = cbf + C_W1L;
  const u16* w1b = cbf + C_W1B;
  int p0 = blockIdx.x * 16;
  int j0 = p0 % 96;
  int rem = p0 / 96;
  int i = rem % 96;
  int b = rem / 96;
  int tid = threadIdx.x;
  int wave = tid >> 6;
  int lane = tid & 63;
  int col = lane & 15;
  int quad = lane >> 4;

  __shared__ float redl[4][16];
  __shared__ float red[4][16][17];

  bf16x8 afrag[4];
  {
    const float* arow = spath + (size_t)(p0 + col) * 128 + quad * 8;
#pragma unroll
    for (int c = 0; c < 4; ++c) {
      bf16x8 f;
#pragma unroll
      for (int q = 0; q < 8; ++q) f[q] = (short)f2bf(arow[32 * c + q]);
      afrag[c] = f;
    }
  }

  float lacc[4] = {0.f, 0.f, 0.f, 0.f};
  float at[4][17];
#pragma unroll
  for (int r = 0; r < 4; ++r)
#pragma unroll
    for (int t = 0; t < 17; ++t) at[r][t] = 0.f;

  const float* LBl_row = LBl + (size_t)(b * 96 + i) * 768;
  const float* LBb_row = LBb + (size_t)(b * 96 + i) * 768;

  for (int nt = wave; nt < 48; nt += 4) {
    int o0 = nt * 16;
    f32x4 c = {0.f, 0.f, 0.f, 0.f};
    const u16* brow = w1l + (size_t)(o0 + col) * 128 + quad * 8;
#pragma unroll
    for (int cc = 0; cc < 4; ++cc) {
      bf16x8 bf = *(const bf16x8*)(brow + 32 * cc);
      c = __builtin_amdgcn_mfma_f32_16x16x32_bf16(afrag[cc], bf, c, 0, 0, 0);
    }
    int o = o0 + col;
    float lb = LBl_row[o];
    float w2 = w2l[o];
#pragma unroll
    for (int r = 0; r < 4; ++r) {
      int m = quad * 4 + r;
      float la = LAl[(size_t)(b * 96 + j0 + m) * 768 + o];
      float h = tanhf(c[r] + la + lb);
      lacc[r] += h * w2;
    }
  }

  for (int nt = wave; nt < 48; nt += 4) {
    int o0 = nt * 16;
    f32x4 c = {0.f, 0.f, 0.f, 0.f};
    const u16* brow = w1b + (size_t)(o0 + col) * 128 + quad * 8;
#pragma unroll
    for (int cc = 0; cc < 4; ++cc) {
      bf16x8 bf = *(const bf16x8*)(brow + 32 * cc);
      c = __builtin_amdgcn_mfma_f32_16x16x32_bf16(afrag[cc], bf, c, 0, 0, 0);
    }
    int o = o0 + col;
    float lb = LBb_row[o];
#pragma unroll
    for (int r = 0; r < 4; ++r) {
      int m = quad * 4 + r;
      float la = LAb[(size_t)(b * 96 + j0 + m) * 768 + o];
      float h = tanhf(c[r] + la + lb);
#pragma unroll
      for (int t = 0; t < 17; ++t) at[r][t] += h * w2b[t * 768 + o];
    }
  }

#pragma unroll
  for (int r = 0; r < 4; ++r) {
    lacc[r] += __shfl_xor(lacc[r], 1, 64);
    lacc[r] += __shfl_xor(lacc[r], 2, 64);
    lacc[r] += __shfl_xor(lacc[r], 4, 64);
    lacc[r] += __shfl_xor(lacc[r], 8, 64);
#pragma unroll
    for (int t = 0; t < 17; ++t) {
      at[r][t] += __shfl_xor(at[r][t], 1, 64);
      at[r][t] += __shfl_xor(at[r][t], 2, 64);
      at[r][t] += __shfl_xor(at[r][t], 4, 64);
      at[r][t] += __shfl_xor(at[r][t], 8, 64);
    }
  }
  if (col == 0) {
#pragma unroll
    for (int r = 0; r < 4; ++r) {
      int m = quad * 4 + r;
      redl[wave][m] = lacc[r];
#pragma unroll
      for (int t = 0; t < 17; ++t) red[wave][m][t] = at[r][t];
    }
  }
  __syncthreads();
  if (tid < 16) {
    float s = redl[0][tid] + redl[1][tid] + redl[2][tid] + redl[3][tid];
    outlink[(size_t)((b * 96 + i) * 96) + j0 + tid] = s + b2l[0];
  }
  for (int task = tid; task < 16 * 17; task += 256) {
    int m = task / 17, t = task % 17;
    float s = red[0][m][t] + red[1][m][t] + red[2][m][t] + red[3][m][t];
    outlab[((size_t)((b * 96 + i) * 96) + j0 + m) * 17 + t] = s + b2b[t];
  }
}

// ================================ launcher ======================================
extern "C" void kernel_launch(void* const* d_in, const int* in_sizes, int n_in,
                              void* d_out, int out_size, void* d_ws, size_t ws_size,
                              hipStream_t stream) {
  (void)in_sizes; (void)n_in; (void)out_size; (void)ws_size;
  const float* sentences = (const float*)d_in[0];
  const int* speakers = (const int*)d_in[1];
  const int* turns = (const int*)d_in[2];
  const int* graphs = (const int*)d_in[3];
  const int* edu_nums = (const int*)d_in[4];
  const float* root = (const float*)d_in[5];
  const float* wih_f = (const float*)d_in[6];
  const float* whh_f = (const float*)d_in[7];
  const float* bih_f = (const float*)d_in[8];
  const float* bhh_f = (const float*)d_in[9];
  const float* wih_b = (const float*)d_in[10];
  const float* whh_b = (const float*)d_in[11];
  const float* bih_b = (const float*)d_in[12];
  const float* bhh_b = (const float*)d_in[13];
  const float* emb_speaker = (const float*)d_in[14];
  const float* emb_turn = (const float*)d_in[15];
  const float* emb_position = (const float*)d_in[16];
  const float* normal_type = (const float*)d_in[17];
  const float* wr = (const float*)d_in[18];
  const float* br = (const float*)d_in[19];
  const float* wz = (const float*)d_in[20];
  const float* bz = (const float*)d_in[21];
  const float* wc = (const float*)d_in[22];
  const float* bc = (const float*)d_in[23];
  const float* wu = (const float*)d_in[24];
  const float* bu = (const float*)d_in[25];
  const float* wq = (const float*)d_in[26];
  const float* wk = (const float*)d_in[27];
  const float* wv = (const float*)d_in[28];
  const float* wo = (const float*)d_in[29];
  const float* bq = (const float*)d_in[30];
  const float* bk = (const float*)d_in[31];
  const float* bv = (const float*)d_in[32];
  const float* bo = (const float*)d_in[33];
  const float* wsk = (const float*)d_in[34];
  const float* bsk = (const float*)d_in[35];
  const float* wsv = (const float*)d_in[36];
  const float* bsv = (const float*)d_in[37];
  const float* ln_s = (const float*)d_in[38];
  const float* ln_b = (const float*)d_in[39];
  const float* pln_s = (const float*)d_in[40];
  const float* pln_b = (const float*)d_in[41];
  const float* link_w1 = (const float*)d_in[42];
  const float* link_b1 = (const float*)d_in[43];
  const float* link_w2 = (const float*)d_in[44];
  const float* link_b2 = (const float*)d_in[45];
  const float* lab_w1 = (const float*)d_in[46];
  const float* lab_b1 = (const float*)d_in[47];
  const float* lab_w2 = (const float*)d_in[48];
  const float* lab_b2 = (const float*)d_in[49];

  int* bar = (int*)d_ws;
  float* W = (float*)((char*)d_ws + 4096);
  float* multi = W + O_MULTI;
  float* xwf = W + O_XWF;
  float* xwb = W + O_XWB;
  float* hbuf = W + O_HBUF;
  float* cpath = W + O_CONST;
  float* spath = W + O_STRUCT;
  float* nodes = W + O_NODES;
  float* qb = W + O_QB;
  float* kb = W + O_KB;
  float* vb = W + O_VB;
  float* skb = W + O_SKB;
  float* svb = W + O_SVB;
  float* np = W + O_NP;
  float* LAl = W + O_LAL;
  float* LBl = W + O_LBL;
  float* LAb = W + O_LAB;
  float* LBb = W + O_LBB;
  u16* l1 = (u16*)(W + O_PATHS);          // link_w1[:, :3072] bf16
  u16* b1 = l1 + 2359296;                  // lab_w1[:, :3072] bf16
  u16* wbf = (u16*)(W + O_END);
  u16* cbf = wbf + B_CBF;
  u16* multibf = wbf + B_MBF;
  u16* nodesbf = wbf + B_NBF;
  u16* attoutbf = wbf + B_ABF;
  float* outlink = (float*)d_out;
  float* outlab = (float*)d_out + 18432;

  init_kernel<<<576, 256, 0, stream>>>(sentences, root, multi, multibf, bar);

  cvt_weights_kernel<<<19456, 256, 0, stream>>>(wq, wk, wv, wo, wih_f, wih_b, wr, wz,
                                                wc, wsk, wsv, wu, link_w1, lab_w1, wbf);

  {  // xw = dialog_input @ wih^T + bih via MFMA
    BJobs j{};
    j.j[0] = {wbf + B_IHF, bih_f, xwf};
    j.j[1] = {wbf + B_IHB, bih_b, xwb};
    bgemm_kernel<<<dim3(12, 18, 2), 256, 0, stream>>>(multibf, 1536, 768, 1152, j);
  }

  init_pairs_kernel<<<9216, 256, 0, stream>>>(speakers, turns, graphs, emb_speaker,
                                              emb_turn, emb_position, normal_type,
                                              cpath, spath);

  // gru (12 blocks) + hidden helpers: layer-0 lnsksv (288) + W1 conversion (84)
  mega_gru_kernel<<<384, 512, 0, stream>>>(whh_f, whh_b, bhh_f, bhh_b, xwf, xwb,
                                           hbuf, multi, multibf, bar, spath, cpath,
                                           pln_s, pln_b, cbf, bsk, bsv, skb, svb,
                                           link_w1, lab_w1, l1, b1);

  for (int layer = 0; layer < 3; ++layer) {
    const u16* nsrcbf = (layer == 0) ? (multibf + 768) : nodesbf;
    int nlda = (layer == 0) ? 1536 : 768;
    const float* nsrc = (layer == 0) ? (multi + 768) : nodes;

    if (layer > 0)
      lnsksv_kernel<<<288, 512, 0, stream>>>(spath, cpath, pln_s, pln_b, cbf, bsk,
                                             bsv, skb, svb, layer == 2 ? 1 : 0);

    {  // q, k, v via MFMA
      BJobs j{};
      j.j[0] = {wbf + B_QW, bq, qb};
      j.j[1] = {wbf + B_KW, bk, kb};
      j.j[2] = {wbf + B_VW, bv, vb};
      bgemm_kernel<<<dim3(12, 12, 3), 256, 0, stream>>>(nsrcbf, nlda, 768, 768, j);
    }

    attn_kernel<<<192, 256, 0, stream>>>(qb, kb, vb, skb, svb, edu_nums, attoutbf);

    oln_kernel<<<12, 256, 0, stream>>>(attoutbf, wbf + B_OW, bo, nsrc, nlda, ln_s,
                                       ln_b, nodes, nodesbf);

    {  // gate pre-projections via MFMA
      BJobs j{};
      j.j[0] = {wbf + B_RA, nullptr, np + 0 * 24576};
      j.j[1] = {wbf + B_RB, nullptr, np + 1 * 24576};
      j.j[2] = {wbf + B_ZA, nullptr, np + 2 * 24576};
      j.j[3] = {wbf + B_ZB, nullptr, np + 3 * 24576};
      j.j[4] = {wbf + B_CA, nullptr, np + 4 * 24576};
      j.j[5] = {wbf + B_CB, nullptr, np + 5 * 24576};
      bgemm_kernel<<<dim3(12, 2, 6), 256, 0, stream>>>(nodesbf, 768, 768, 128, j);
    }

    gate_mfma_kernel<<<570, 256, 0, stream>>>(spath, np, cbf, br, bz, bc, bu);
  }

  {  // LA/LB via MFMA, K=1536 (l1/b1 were converted under the gru launch)
    BJobs j{};
    j.j[0] = {l1, link_b1, LAl};
    j.j[1] = {l1 + 1179648, nullptr, LBl};
    j.j[2] = {b1, lab_b1, LAb};
    j.j[3] = {b1 + 1179648, nullptr, LBb};
    bgemm_kernel<<<dim3(12, 12, 4), 256, 0, stream>>>(multibf, 1536, 1536, 768, j);
  }

  final_mfma_kernel<<<1152, 256, 0, stream>>>(spath, cbf, LAl, LBl, LAb, LBb,
                                              link_w2, lab_w2, link_b2, lab_b2,
                                              outlink, outlab);
}

// Round 10
// 991.840 us; speedup vs baseline: 1.0950x; 1.0950x over previous
//
#include <hip/hip_runtime.h>
#include <math.h>

typedef unsigned short u16;
typedef short bf16x8 __attribute__((ext_vector_type(8)));
typedef float f32x4 __attribute__((ext_vector_type(4)));

// Shapes: B=2, N=96, H=768, H2=384, P=128, HEADS=12, D=64, T=17, CIN=3200
// PAIRS = 18432 ; tril pairs = 9120

// ---------------- workspace layout (floats, after 4KB header) ------------------
static constexpr size_t O_MULTI  = 0;                       // (192,1536)
static constexpr size_t O_XWF    = O_MULTI + 294912;        // (192,1152)
static constexpr size_t O_XWB    = O_XWF   + 221184;
static constexpr size_t O_HBUF   = O_XWB   + 221184;
static constexpr size_t O_CONST  = O_HBUF  + 3072;          // (18432,128)
static constexpr size_t O_STRUCT = O_CONST + 2359296;       // (18432,128)
static constexpr size_t O_PATHS  = O_STRUCT+ 2359296;       // l1/b1 bf16 (9.4MB)
static constexpr size_t O_NODES  = O_PATHS + 2359296;
static constexpr size_t O_QB     = O_NODES + 147456;
static constexpr size_t O_KB     = O_QB    + 147456;
static constexpr size_t O_VB     = O_KB    + 147456;
static constexpr size_t O_SKB    = O_VB    + 147456;        // (18432,64)
static constexpr size_t O_SVB    = O_SKB   + 1179648;
static constexpr size_t O_ATT    = O_SVB   + 1179648;
static constexpr size_t O_NP     = O_ATT   + 147456;        // 6 x (192,128)
static constexpr size_t O_LAL    = O_NP    + 147456;
static constexpr size_t O_LBL    = O_LAL   + 147456;
static constexpr size_t O_LAB    = O_LBL   + 147456;
static constexpr size_t O_LBB    = O_LAB   + 147456;
static constexpr size_t O_END    = O_LBB   + 147456;        // 11652096 floats

// bf16 weight region WBF (u16 units), placed after O_END
static constexpr int B_QW  = 0;          // 768x768
static constexpr int B_KW  = 589824;
static constexpr int B_VW  = 1179648;
static constexpr int B_OW  = 1769472;
static constexpr int B_IHF = 2359296;    // 1152x768
static constexpr int B_IHB = 3244032;
static constexpr int B_RA  = 4128768;    // 128x768 (wr cols 0:768)
static constexpr int B_RB  = 4227072;    // wr cols 768:1536
static constexpr int B_ZA  = 4325376;
static constexpr int B_ZB  = 4423680;
static constexpr int B_CA  = 4521984;    // wc cols 0:768
static constexpr int B_CB  = 4620288;
static constexpr int B_CBF = 4718592;    // 262144: wsk|wsv|wrs|wzs|wu|w1l|w1b
static constexpr int B_MBF = 4980736;    // multibf (192,1536)
static constexpr int B_NBF = 5275648;    // nodesbf (192,768)
static constexpr int B_ABF = 5423104;    // attoutbf (192,768)
static constexpr int CVT_TOT = 4980736;  // converted by cvt_weights

// offsets inside CBF (relative)
static constexpr int C_WSK = 0;
static constexpr int C_WSV = 8192;
static constexpr int C_WRS = 16384;
static constexpr int C_WZS = 32768;
static constexpr int C_WU  = 49152;
static constexpr int C_W1L = 65536;
static constexpr int C_W1B = 163840;

__device__ __forceinline__ u16 f2bf(float f) {
  union { float f; unsigned u; } v; v.f = f;
  unsigned r = v.u + 0x7fff + ((v.u >> 16) & 1);
  return (u16)(r >> 16);
}

// ---------------- init: dialog_input into multi (+bf16); zero flags ------------
__global__ void init_kernel(const float* __restrict__ sentences,
                            const float* __restrict__ root,
                            float* __restrict__ multi, u16* __restrict__ multibf,
                            int* bar) {
  int idx = blockIdx.x * 256 + threadIdx.x;
  if (idx < 12) bar[idx * 64] = 0;
  if (idx >= 2 * 96 * 768) return;
  int c = idx % 768;
  int rem = idx / 768;
  int t = rem % 96;
  int b = rem / 96;
  float v = (t == 0) ? root[c] : sentences[((size_t)(b * 95 + (t - 1))) * 768 + c];
  size_t a = ((size_t)(b * 96 + t)) * 1536 + c;
  multi[a] = v;
  multibf[a] = f2bf(v);
}

// ---------------- const_path + struct_path init --------------------------------
__global__ void init_pairs_kernel(const int* __restrict__ speakers,
                                  const int* __restrict__ turns,
                                  const int* __restrict__ graphs,
                                  const float* __restrict__ emb_speaker,
                                  const float* __restrict__ emb_turn,
                                  const float* __restrict__ emb_position,
                                  const float* __restrict__ normal_type,
                                  float* __restrict__ cpath,
                                  float* __restrict__ spath) {
  int idx = blockIdx.x * 256 + threadIdx.x;
  if (idx >= 18432 * 128) return;
  int c = idx & 127;
  int p = idx >> 7;
  int j = p % 96;
  int rem = p / 96;
  int i = rem % 96;
  int b = rem / 96;
  float cv;
  if (c < 32) {
    cv = emb_speaker[speakers[p] * 32 + c];
  } else if (c < 64) {
    cv = emb_turn[turns[p] * 32 + (c - 32)];
  } else {
    int d = j - i;
    d = min(max(d, -11), 11) + 11;
    cv = emb_position[d * 64 + (c - 64)];
  }
  cpath[idx] = cv;
  int g2 = graphs[p] + graphs[(b * 96 + j) * 96 + i];
  spath[idx] = (g2 == 0) ? 0.f : normal_type[(g2 - 1) * 128 + c];
}

// ---------------- convert all persistent weights to bf16 -----------------------
__global__ void cvt_weights_kernel(const float* __restrict__ wq, const float* __restrict__ wk,
                                   const float* __restrict__ wv, const float* __restrict__ wo,
                                   const float* __restrict__ wih_f, const float* __restrict__ wih_b,
                                   const float* __restrict__ wr, const float* __restrict__ wz,
                                   const float* __restrict__ wc, const float* __restrict__ wsk,
                                   const float* __restrict__ wsv, const float* __restrict__ wu,
                                   const float* __restrict__ link_w1, const float* __restrict__ lab_w1,
                                   u16* __restrict__ wbf) {
  int idx = blockIdx.x * 256 + threadIdx.x;
  if (idx >= CVT_TOT) return;
  float v;
  if (idx < B_IHF) {
    int which = idx / 589824, r = idx % 589824;
    const float* src = which == 0 ? wq : which == 1 ? wk : which == 2 ? wv : wo;
    v = src[r];
  } else if (idx < B_RA) {
    int r = idx - B_IHF;
    v = (r < 884736) ? wih_f[r] : wih_b[r - 884736];
  } else if (idx < B_CBF) {
    int r = idx - B_RA;
    int seg = r / 98304, q = r % 98304;
    int row = q / 768, c = q % 768;
    switch (seg) {
      case 0: v = wr[(size_t)row * 1664 + c]; break;
      case 1: v = wr[(size_t)row * 1664 + 768 + c]; break;
      case 2: v = wz[(size_t)row * 1664 + c]; break;
      case 3: v = wz[(size_t)row * 1664 + 768 + c]; break;
      case 4: v = wc[(size_t)row * 1536 + c]; break;
      default: v = wc[(size_t)row * 1536 + 768 + c]; break;
    }
  } else {
    int r = idx - B_CBF;
    if (r < C_WSV) v = wsk[r];
    else if (r < C_WRS) v = wsv[r - C_WSV];
    else if (r < C_WZS) { int q = r - C_WRS; v = wr[(size_t)(q >> 7) * 1664 + 1536 + (q & 127)]; }
    else if (r < C_WU)  { int q = r - C_WZS; v = wz[(size_t)(q >> 7) * 1664 + 1536 + (q & 127)]; }
    else if (r < C_W1L) v = wu[r - C_WU];
    else if (r < C_W1B) { int q = r - C_W1L; v = link_w1[(size_t)(q >> 7) * 3200 + 3072 + (q & 127)]; }
    else { int q = r - C_W1B; v = lab_w1[(size_t)(q >> 7) * 3200 + 3072 + (q & 127)]; }
  }
  wbf[idx] = f2bf(v);
}

// ---------------- generic MFMA GEMM: C = A(bf16) @ W(bf16)^T (+bias) -----------
struct BJob { const u16* W; const float* bias; float* C; };
struct BJobs { BJob j[6]; };

__global__ __launch_bounds__(256) void bgemm_kernel(const u16* __restrict__ A,
                                                    int lda, int K, int N, BJobs jobs) {
  BJob jb = jobs.j[blockIdx.z];
  int r0 = blockIdx.x * 16;
  int tid = threadIdx.x;
  int wave = tid >> 6, lane = tid & 63;
  int col = lane & 15, quad = lane >> 4;
  int c = blockIdx.y * 64 + wave * 16 + col;
  const u16* arow = A + (size_t)(r0 + col) * lda + quad * 8;
  const u16* brow = jb.W + (size_t)c * K + quad * 8;
  f32x4 acc = {0.f, 0.f, 0.f, 0.f};
  for (int k = 0; k < K; k += 32) {
    bf16x8 af = *(const bf16x8*)(arow + k);
    bf16x8 bf = *(const bf16x8*)(brow + k);
    acc = __builtin_amdgcn_mfma_f32_16x16x32_bf16(af, bf, acc, 0, 0, 0);
  }
  float bv = jb.bias ? jb.bias[c] : 0.f;
#pragma unroll
  for (int r = 0; r < 4; ++r)
    jb.C[(size_t)(r0 + quad * 4 + r) * N + c] = acc[r] + bv;
}

// ------- fused symmetrize + LN(struct+const) + sk/sv MFMA (64 pairs/block) -----
__device__ __forceinline__ void lnsksv_body(int blk, int tid,
                                            float* __restrict__ spath,
                                            const float* __restrict__ cpath,
                                            const float* __restrict__ pln_s,
                                            const float* __restrict__ pln_b,
                                            const u16* __restrict__ cbf,
                                            const float* __restrict__ bsk,
                                            const float* __restrict__ bsv,
                                            float* __restrict__ skb,
                                            float* __restrict__ svb,
                                            int store_upper, u16* plds) {
  int p0 = blk * 64;
  int wave = tid >> 6, lane = tid & 63;
  float pls0 = pln_s[lane], pls1 = pln_s[lane + 64];
  float plb0 = pln_b[lane], plb1 = pln_b[lane + 64];
#pragma unroll
  for (int pp = 0; pp < 8; ++pp) {
    int pl = wave * 8 + pp;
    int p = p0 + pl;
    int j = p % 96;
    int rem = p / 96;
    int i = rem % 96;
    int b = rem / 96;
    size_t self = (size_t)p * 128;
    const float* src = (i < j) ? (spath + ((size_t)((b * 96 + j) * 96 + i)) * 128)
                               : (spath + self);
    float v0 = src[lane], v1 = src[lane + 64];
    if (store_upper && i < j) {
      spath[self + lane] = v0;
      spath[self + lane + 64] = v1;
    }
    float x0 = v0 + cpath[self + lane];
    float x1 = v1 + cpath[self + lane + 64];
    float s = x0 + x1;
    for (int off = 32; off; off >>= 1) s += __shfl_xor(s, off, 64);
    float mean = s * (1.f / 128.f);
    float d0 = x0 - mean, d1 = x1 - mean;
    float vs = d0 * d0 + d1 * d1;
    for (int off = 32; off; off >>= 1) vs += __shfl_xor(vs, off, 64);
    float rstd = rsqrtf(vs * (1.f / 128.f) + 1e-5f);
    plds[pl * 136 + lane] = f2bf(d0 * rstd * pls0 + plb0);
    plds[pl * 136 + lane + 64] = f2bf(d1 * rstd * pls1 + plb1);
  }
  __syncthreads();
  int mat = wave >> 2, rowg = wave & 3;
  const u16* wb = cbf + (mat ? C_WSV : C_WSK);
  const float* bias = mat ? bsv : bsk;
  float* out = mat ? svb : skb;
  int col = lane & 15, quad = lane >> 4;
  bf16x8 afrag[4];
  const u16* arow = plds + (rowg * 16 + col) * 136 + quad * 8;
#pragma unroll
  for (int c = 0; c < 4; ++c) afrag[c] = *(const bf16x8*)(arow + 32 * c);
#pragma unroll
  for (int nt = 0; nt < 4; ++nt) {
    f32x4 acc = {0.f, 0.f, 0.f, 0.f};
    const u16* brow = wb + (size_t)(nt * 16 + col) * 128 + quad * 8;
#pragma unroll
    for (int c = 0; c < 4; ++c)
      acc = __builtin_amdgcn_mfma_f32_16x16x32_bf16(afrag[c], *(const bf16x8*)(brow + 32 * c), acc, 0, 0, 0);
    int o = nt * 16 + col;
    float bv = bias[o];
#pragma unroll
    for (int r = 0; r < 4; ++r)
      out[(size_t)(p0 + rowg * 16 + quad * 4 + r) * 64 + o] = acc[r] + bv;
  }
}

__global__ __launch_bounds__(512) void lnsksv_kernel(float* __restrict__ spath,
                                                     const float* __restrict__ cpath,
                                                     const float* __restrict__ pln_s,
                                                     const float* __restrict__ pln_b,
                                                     const u16* __restrict__ cbf,
                                                     const float* __restrict__ bsk,
                                                     const float* __restrict__ bsv,
                                                     float* __restrict__ skb,
                                                     float* __restrict__ svb,
                                                     int store_upper) {
  __shared__ u16 plds[64 * 136];
  lnsksv_body(blockIdx.x, threadIdx.x, spath, cpath, pln_s, pln_b, cbf, bsk, bsv,
              skb, svb, store_upper, plds);
}

// ---------------- mega kernel: gru (12 blocks) + hidden helpers ----------------
__global__ __launch_bounds__(512) void mega_gru_kernel(
    const float* __restrict__ whh_f, const float* __restrict__ whh_b,
    const float* __restrict__ bhh_f, const float* __restrict__ bhh_b,
    const float* __restrict__ xwf, const float* __restrict__ xwb,
    float* hbuf, float* multi, u16* multibf, int* bar,
    float* __restrict__ spath, const float* __restrict__ cpath,
    const float* __restrict__ pln_s, const float* __restrict__ pln_b,
    const u16* __restrict__ cbf, const float* __restrict__ bsk,
    const float* __restrict__ bsv, float* __restrict__ skb,
    float* __restrict__ svb, const float* __restrict__ link_w1,
    const float* __restrict__ lab_w1, u16* __restrict__ l1, u16* __restrict__ b1) {
  __shared__ float hlds[768];
  __shared__ float part[3][64][2][17];
  __shared__ u16 plds[64 * 136];
  int bx = blockIdx.x;
  int tid = threadIdx.x;

  if (bx >= 300) {  // W1 conversion helpers
    for (int idx = (bx - 300) * 512 + tid; idx < 2359296; idx += 84 * 512) {
      int half = idx / 1179648;
      int r = idx % 1179648;
      int row = r / 1536, c = r % 1536;
      size_t src = (size_t)row * 3200 + half * 1536 + c;
      l1[idx] = f2bf(link_w1[src]);
      b1[idx] = f2bf(lab_w1[src]);
    }
    return;
  }
  if (bx >= 12) {  // layer-0 lnsksv helpers
    lnsksv_body(bx - 12, tid, spath, cpath, pln_s, pln_b, cbf, bsk, bsv, skb, svb,
                0, plds);
    return;
  }

  // ---- gru role ----
  int dir = bx / 6;
  int sub = bx % 6;
  const float* whh = dir ? whh_b : whh_f;
  const float* bhh = dir ? bhh_b : bhh_f;
  const float* xw = dir ? xwb : xwf;
  float* hb = hbuf + (size_t)dir * 1536;
  int* flags = bar + dir * 6 * 64;

  int ks = tid >> 5;
  int ug = tid & 31;
  int hv0 = ug * 2;

  float4 wreg[6][6];
#pragma unroll
  for (int d = 0; d < 2; ++d)
#pragma unroll
    for (int g = 0; g < 3; ++g) {
      const float* wrow = whh + (size_t)(g * 384 + sub * 64 + hv0 + d) * 384 + ks * 24;
#pragma unroll
      for (int m = 0; m < 6; ++m) wreg[d * 3 + g][m] = *(const float4*)(wrow + m * 4);
    }
  float bh0 = 0.f, bh1 = 0.f, bh2 = 0.f;
  int hvC = 0, bsel = 0;
  if (tid < 128) {
    hvC = sub * 64 + (tid >> 1);
    bsel = tid & 1;
    bh0 = bhh[hvC];
    bh1 = bhh[384 + hvC];
    bh2 = bhh[768 + hvC];
  }

  for (int s = 0; s < 96; ++s) {
    int t = dir ? (95 - s) : s;
    float xr = 0.f, xz = 0.f, xn = 0.f;
    if (tid < 128) {
      const float* xrow = xw + (size_t)(bsel * 96 + t) * 1152;
      xr = xrow[hvC]; xz = xrow[384 + hvC]; xn = xrow[768 + hvC];
    }
    if (s == 0) {
      __syncthreads();
      for (int k = tid; k < 768; k += 512) hlds[k] = 0.f;
    } else {
      if (tid < 6) {
        while (__hip_atomic_load(&flags[tid * 64], __ATOMIC_RELAXED,
                                 __HIP_MEMORY_SCOPE_AGENT) < s)
          __builtin_amdgcn_s_sleep(1);
      }
      __syncthreads();
      const float* hsrc = hb + ((s - 1) & 1) * 768;
      for (int k = tid; k < 768; k += 512)
        hlds[k] = __hip_atomic_load(&hsrc[k], __ATOMIC_RELAXED, __HIP_MEMORY_SCOPE_AGENT);
    }
    __syncthreads();

    float acc[6][2];
#pragma unroll
    for (int b = 0; b < 2; ++b) {
      float4 h4[6];
      const float* hp = hlds + b * 384 + ks * 24;
#pragma unroll
      for (int m = 0; m < 6; ++m) h4[m] = *(const float4*)(hp + m * 4);
#pragma unroll
      for (int u = 0; u < 6; ++u) {
        float ssum = 0.f;
#pragma unroll
        for (int m = 0; m < 6; ++m) {
          float4 w = wreg[u][m];
          ssum += w.x * h4[m].x + w.y * h4[m].y + w.z * h4[m].z + w.w * h4[m].w;
        }
        acc[u][b] = ssum;
      }
    }
#pragma unroll
    for (int d = 0; d < 2; ++d)
#pragma unroll
      for (int g = 0; g < 3; ++g) {
        part[g][hv0 + d][0][ks] = acc[d * 3 + g][0];
        part[g][hv0 + d][1][ks] = acc[d * 3 + g][1];
      }
    __syncthreads();

    float hn = 0.f;
    if (tid < 128) {
      int hv = tid >> 1;
      float gr = bh0, gz = bh1, gn = bh2;
#pragma unroll
      for (int q = 0; q < 16; ++q) {
        gr += part[0][hv][bsel][q];
        gz += part[1][hv][bsel][q];
        gn += part[2][hv][bsel][q];
      }
      float r = 1.f / (1.f + expf(-(xr + gr)));
      float z = 1.f / (1.f + expf(-(xz + gz)));
      float n = tanhf(xn + r * gn);
      float hp = hlds[bsel * 384 + hvC];
      hn = (1.f - z) * n + z * hp;
      __hip_atomic_store(&hb[(s & 1) * 768 + bsel * 384 + hvC], hn, __ATOMIC_RELAXED,
                         __HIP_MEMORY_SCOPE_AGENT);
    }
    asm volatile("s_waitcnt vmcnt(0)" ::: "memory");
    __syncthreads();
    if (tid == 0)
      __hip_atomic_store(&flags[sub * 64], s + 1, __ATOMIC_RELAXED,
                         __HIP_MEMORY_SCOPE_AGENT);
    if (tid < 128) {
      size_t a = ((size_t)(bsel * 96 + t)) * 1536 + 768 + dir * 384 + hvC;
      multi[a] = hn;
      multibf[a] = f2bf(hn);
    }
  }
}

// ---------------- fused attention per (b,i), bf16 output ------------------------
__global__ __launch_bounds__(256) void attn_kernel(const float* __restrict__ qb,
                                                   const float* __restrict__ kb,
                                                   const float* __restrict__ vb,
                                                   const float* __restrict__ skb,
                                                   const float* __restrict__ svb,
                                                   const int* __restrict__ edu_nums,
                                                   u16* __restrict__ attout) {
  int bi = blockIdx.x;
  int b = bi / 96;
  __shared__ float qrow[768];
  __shared__ float sc[12][100];
  int tid = threadIdx.x;
  for (int k = tid; k < 768; k += 256) qrow[k] = qb[(size_t)bi * 768 + k];
  int edun = edu_nums[b];
  __syncthreads();
  for (int task = tid; task < 12 * 96; task += 256) {
    int h = task / 96, j = task % 96;
    const float* krow = kb + ((size_t)(b * 96 + j)) * 768 + h * 64;
    const float* skrow = skb + ((size_t)(bi * 96 + j)) * 64;
    float s = 0.f;
    for (int d4 = 0; d4 < 64; d4 += 4) {
      float4 qv = *(const float4*)(qrow + h * 64 + d4);
      float4 kv = *(const float4*)(krow + d4);
      float4 sv = *(const float4*)(skrow + d4);
      s += qv.x * (kv.x + sv.x) + qv.y * (kv.y + sv.y) + qv.z * (kv.z + sv.z) +
           qv.w * (kv.w + sv.w);
    }
    s *= 0.125f;
    if (j >= edun) s -= 1e9f;
    sc[h][j] = s;
  }
  __syncthreads();
  if (tid < 12) {
    int h = tid;
    float m = -3.4e38f;
    for (int j = 0; j < 96; ++j) m = fmaxf(m, sc[h][j]);
    float sum = 0.f;
    for (int j = 0; j < 96; ++j) {
      float e = expf(sc[h][j] - m);
      sc[h][j] = e;
      sum += e;
    }
    float r = 1.f / sum;
    for (int j = 0; j < 96; ++j) sc[h][j] *= r;
  }
  __syncthreads();
  for (int o = tid; o < 768; o += 256) {
    int h = o >> 6, d = o & 63;
    float acc = 0.f;
    const float* vcol = vb + (size_t)(b * 96) * 768 + o;
    const float* svcol = svb + ((size_t)(bi * 96)) * 64 + d;
    for (int j = 0; j < 96; ++j) acc += sc[h][j] * (vcol[j * 768] + svcol[j * 64]);
    attout[(size_t)bi * 768 + o] = f2bf(acc);
  }
}

// ---------------- nodes = LN(src + relu(proj)), fp32 + bf16 out -----------------
__global__ __launch_bounds__(256) void ln_nodes_kernel(const float* __restrict__ src,
                                                       int lda,
                                                       const float* __restrict__ proj,
                                                       const float* __restrict__ ln_s,
                                                       const float* __restrict__ ln_b,
                                                       float* __restrict__ nodes,
                                                       u16* __restrict__ nodesbf) {
  int row = blockIdx.x * 4 + (threadIdx.x >> 6);
  int lane = threadIdx.x & 63;
  float x[12];
  float s = 0.f;
#pragma unroll
  for (int m = 0; m < 12; ++m) {
    int e = lane + m * 64;
    float v = src[(size_t)row * lda + e] + fmaxf(proj[(size_t)row * 768 + e], 0.f);
    x[m] = v;
    s += v;
  }
  for (int off = 32; off; off >>= 1) s += __shfl_xor(s, off, 64);
  float mean = s * (1.f / 768.f);
  float vs = 0.f;
#pragma unroll
  for (int m = 0; m < 12; ++m) {
    float d = x[m] - mean;
    x[m] = d;
    vs += d * d;
  }
  for (int off = 32; off; off >>= 1) vs += __shfl_xor(vs, off, 64);
  float rstd = rsqrtf(vs * (1.f / 768.f) + 1e-5f);
#pragma unroll
  for (int m = 0; m < 12; ++m) {
    int e = lane + m * 64;
    float v = x[m] * rstd * ln_s[e] + ln_b[e];
    nodes[(size_t)row * 768 + e] = v;
    nodesbf[(size_t)row * 768 + e] = f2bf(v);
  }
}

// ---------------- pairwise gate update via MFMA (tril pairs) --------------------
__global__ __launch_bounds__(256) void gate_mfma_kernel(float* __restrict__ spath,
                                                        const float* __restrict__ np,
                                                        const u16* __restrict__ cbf,
                                                        const float* __restrict__ br,
                                                        const float* __restrict__ bz,
                                                        const float* __restrict__ bc,
                                                        const float* __restrict__ bu) {
  __shared__ int addrs[16], npi[16], npj[16];
  int tid = threadIdx.x;
  if (tid < 16) {
    int pid = blockIdx.x * 16 + tid;
    int b = pid / 4560;
    int t = pid % 4560;
    int i = (int)((sqrtf(8.f * (float)t + 1.f) + 1.f) * 0.5f);
    while (i * (i - 1) / 2 > t) --i;
    while ((i + 1) * i / 2 <= t) ++i;
    int j = t - i * (i - 1) / 2;
    addrs[tid] = ((b * 96 + i) * 96 + j) * 128;
    npi[tid] = (b * 96 + i) * 128;
    npj[tid] = (b * 96 + j) * 128;
  }
  __syncthreads();

  int wave = tid >> 6, lane = tid & 63;
  int col = lane & 15, quad = lane >> 4;

  bf16x8 afrag[4];
  {
    const float* arow = spath + (size_t)addrs[col] + quad * 8;
#pragma unroll
    for (int c = 0; c < 4; ++c) {
      bf16x8 f;
#pragma unroll
      for (int q = 0; q < 8; ++q) f[q] = (short)f2bf(arow[32 * c + q]);
      afrag[c] = f;
    }
  }

  const u16* wrs = cbf + C_WRS;
  const u16* wzs = cbf + C_WZS;
  const u16* wu = cbf + C_WU;

  f32x4 cr[2], cz[2], cu[2];
#pragma unroll
  for (int ct = 0; ct < 2; ++ct) {
    cr[ct] = {0.f, 0.f, 0.f, 0.f};
    cz[ct] = {0.f, 0.f, 0.f, 0.f};
    cu[ct] = {0.f, 0.f, 0.f, 0.f};
    int o0 = wave * 32 + ct * 16;
    const u16* br_ = wrs + (size_t)(o0 + col) * 128 + quad * 8;
    const u16* bz_ = wzs + (size_t)(o0 + col) * 128 + quad * 8;
    const u16* bu_ = wu + (size_t)(o0 + col) * 128 + quad * 8;
#pragma unroll
    for (int c = 0; c < 4; ++c) {
      cr[ct] = __builtin_amdgcn_mfma_f32_16x16x32_bf16(afrag[c], *(const bf16x8*)(br_ + 32 * c), cr[ct], 0, 0, 0);
      cz[ct] = __builtin_amdgcn_mfma_f32_16x16x32_bf16(afrag[c], *(const bf16x8*)(bz_ + 32 * c), cz[ct], 0, 0, 0);
      cu[ct] = __builtin_amdgcn_mfma_f32_16x16x32_bf16(afrag[c], *(const bf16x8*)(bu_ + 32 * c), cu[ct], 0, 0, 0);
    }
  }

#pragma unroll
  for (int ct = 0; ct < 2; ++ct) {
    int o = wave * 32 + ct * 16 + col;
    float brv = br[o], bzv = bz[o], bcv = bc[o], buv = bu[o];
#pragma unroll
    for (int r4 = 0; r4 < 4; ++r4) {
      int m = quad * 4 + r4;
      int sa = addrs[m] + o;
      float so = spath[sa];
      float nra = np[0 * 24576 + npj[m] + o];
      float nrb = np[1 * 24576 + npi[m] + o];
      float nza = np[2 * 24576 + npj[m] + o];
      float nzb = np[3 * 24576 + npi[m] + o];
      float nca = np[4 * 24576 + npj[m] + o];
      float ncb = np[5 * 24576 + npi[m] + o];
      float r = 1.f / (1.f + expf(-(cr[ct][r4] + nra + nrb + brv)));
      float z = 1.f / (1.f + expf(-(cz[ct][r4] + nza + nzb + bzv)));
      float u = tanhf(nca + ncb + bcv + r * (cu[ct][r4] + buv));
      spath[sa] = z * so + (1.f - z) * u;
    }
  }
}

// ---------------- final fused link/label head (MFMA, converts spath inline) ----
__global__ __launch_bounds__(256) void final_mfma_kernel(
    const float* __restrict__ spath, const u16* __restrict__ cbf,
    const float* __restrict__ LAl, const float* __restrict__ LBl,
    const float* __restrict__ LAb, const float* __restrict__ LBb,
    const float* __restrict__ w2l, const float* __restrict__ w2b,
    const float* __restrict__ b2l, const float* __restrict__ b2b,
    float* __restrict__ outlink, float* __restrict__ outlab) {
  const u16* w1l = cbf + C_W1L;
  const u16* w1b = cbf + C_W1B;
  int p0 = blockIdx.x * 16;
  int j0 = p0 % 96;
  int rem = p0 / 96;
  int i = rem % 96;
  int b = rem / 96;
  int tid = threadIdx.x;
  int wave = tid >> 6;
  int lane = tid & 63;
  int col = lane & 15;
  int quad = lane >> 4;

  __shared__ float redl[4][16];
  __shared__ float red[4][16][17];

  bf16x8 afrag[4];
  {
    const float* arow = spath + (size_t)(p0 + col) * 128 + quad * 8;
#pragma unroll
    for (int c = 0; c < 4; ++c) {
      bf16x8 f;
#pragma unroll
      for (int q = 0; q < 8; ++q) f[q] = (short)f2bf(arow[32 * c + q]);
      afrag[c] = f;
    }
  }

  float lacc[4] = {0.f, 0.f, 0.f, 0.f};
  float at[4][17];
#pragma unroll
  for (int r = 0; r < 4; ++r)
#pragma unroll
    for (int t = 0; t < 17; ++t) at[r][t] = 0.f;

  const float* LBl_row = LBl + (size_t)(b * 96 + i) * 768;
  const float* LBb_row = LBb + (size_t)(b * 96 + i) * 768;

  for (int nt = wave; nt < 48; nt += 4) {
    int o0 = nt * 16;
    f32x4 c = {0.f, 0.f, 0.f, 0.f};
    const u16* brow = w1l + (size_t)(o0 + col) * 128 + quad * 8;
#pragma unroll
    for (int cc = 0; cc < 4; ++cc) {
      bf16x8 bf = *(const bf16x8*)(brow + 32 * cc);
      c = __builtin_amdgcn_mfma_f32_16x16x32_bf16(afrag[cc], bf, c, 0, 0, 0);
    }
    int o = o0 + col;
    float lb = LBl_row[o];
    float w2 = w2l[o];
#pragma unroll
    for (int r = 0; r < 4; ++r) {
      int m = quad * 4 + r;
      float la = LAl[(size_t)(b * 96 + j0 + m) * 768 + o];
      float h = tanhf(c[r] + la + lb);
      lacc[r] += h * w2;
    }
  }

  for (int nt = wave; nt < 48; nt += 4) {
    int o0 = nt * 16;
    f32x4 c = {0.f, 0.f, 0.f, 0.f};
    const u16* brow = w1b + (size_t)(o0 + col) * 128 + quad * 8;
#pragma unroll
    for (int cc = 0; cc < 4; ++cc) {
      bf16x8 bf = *(const bf16x8*)(brow + 32 * cc);
      c = __builtin_amdgcn_mfma_f32_16x16x32_bf16(afrag[cc], bf, c, 0, 0, 0);
    }
    int o = o0 + col;
    float lb = LBb_row[o];
#pragma unroll
    for (int r = 0; r < 4; ++r) {
      int m = quad * 4 + r;
      float la = LAb[(size_t)(b * 96 + j0 + m) * 768 + o];
      float h = tanhf(c[r] + la + lb);
#pragma unroll
      for (int t = 0; t < 17; ++t) at[r][t] += h * w2b[t * 768 + o];
    }
  }

#pragma unroll
  for (int r = 0; r < 4; ++r) {
    lacc[r] += __shfl_xor(lacc[r], 1, 64);
    lacc[r] += __shfl_xor(lacc[r], 2, 64);
    lacc[r] += __shfl_xor(lacc[r], 4, 64);
    lacc[r] += __shfl_xor(lacc[r], 8, 64);
#pragma unroll
    for (int t = 0; t < 17; ++t) {
      at[r][t] += __shfl_xor(at[r][t], 1, 64);
      at[r][t] += __shfl_xor(at[r][t], 2, 64);
      at[r][t] += __shfl_xor(at[r][t], 4, 64);
      at[r][t] += __shfl_xor(at[r][t], 8, 64);
    }
  }
  if (col == 0) {
#pragma unroll
    for (int r = 0; r < 4; ++r) {
      int m = quad * 4 + r;
      redl[wave][m] = lacc[r];
#pragma unroll
      for (int t = 0; t < 17; ++t) red[wave][m][t] = at[r][t];
    }
  }
  __syncthreads();
  if (tid < 16) {
    float s = redl[0][tid] + redl[1][tid] + redl[2][tid] + redl[3][tid];
    outlink[(size_t)((b * 96 + i) * 96) + j0 + tid] = s + b2l[0];
  }
  for (int task = tid; task < 16 * 17; task += 256) {
    int m = task / 17, t = task % 17;
    float s = red[0][m][t] + red[1][m][t] + red[2][m][t] + red[3][m][t];
    outlab[((size_t)((b * 96 + i) * 96) + j0 + m) * 17 + t] = s + b2b[t];
  }
}

// ================================ launcher ======================================
extern "C" void kernel_launch(void* const* d_in, const int* in_sizes, int n_in,
                              void* d_out, int out_size, void* d_ws, size_t ws_size,
                              hipStream_t stream) {
  (void)in_sizes; (void)n_in; (void)out_size; (void)ws_size;
  const float* sentences = (const float*)d_in[0];
  const int* speakers = (const int*)d_in[1];
  const int* turns = (const int*)d_in[2];
  const int* graphs = (const int*)d_in[3];
  const int* edu_nums = (const int*)d_in[4];
  const float* root = (const float*)d_in[5];
  const float* wih_f = (const float*)d_in[6];
  const float* whh_f = (const float*)d_in[7];
  const float* bih_f = (const float*)d_in[8];
  const float* bhh_f = (const float*)d_in[9];
  const float* wih_b = (const float*)d_in[10];
  const float* whh_b = (const float*)d_in[11];
  const float* bih_b = (const float*)d_in[12];
  const float* bhh_b = (const float*)d_in[13];
  const float* emb_speaker = (const float*)d_in[14];
  const float* emb_turn = (const float*)d_in[15];
  const float* emb_position = (const float*)d_in[16];
  const float* normal_type = (const float*)d_in[17];
  const float* wr = (const float*)d_in[18];
  const float* br = (const float*)d_in[19];
  const float* wz = (const float*)d_in[20];
  const float* bz = (const float*)d_in[21];
  const float* wc = (const float*)d_in[22];
  const float* bc = (const float*)d_in[23];
  const float* wu = (const float*)d_in[24];
  const float* bu = (const float*)d_in[25];
  const float* wq = (const float*)d_in[26];
  const float* wk = (const float*)d_in[27];
  const float* wv = (const float*)d_in[28];
  const float* wo = (const float*)d_in[29];
  const float* bq = (const float*)d_in[30];
  const float* bk = (const float*)d_in[31];
  const float* bv = (const float*)d_in[32];
  const float* bo = (const float*)d_in[33];
  const float* wsk = (const float*)d_in[34];
  const float* bsk = (const float*)d_in[35];
  const float* wsv = (const float*)d_in[36];
  const float* bsv = (const float*)d_in[37];
  const float* ln_s = (const float*)d_in[38];
  const float* ln_b = (const float*)d_in[39];
  const float* pln_s = (const float*)d_in[40];
  const float* pln_b = (const float*)d_in[41];
  const float* link_w1 = (const float*)d_in[42];
  const float* link_b1 = (const float*)d_in[43];
  const float* link_w2 = (const float*)d_in[44];
  const float* link_b2 = (const float*)d_in[45];
  const float* lab_w1 = (const float*)d_in[46];
  const float* lab_b1 = (const float*)d_in[47];
  const float* lab_w2 = (const float*)d_in[48];
  const float* lab_b2 = (const float*)d_in[49];

  int* bar = (int*)d_ws;
  float* W = (float*)((char*)d_ws + 4096);
  float* multi = W + O_MULTI;
  float* xwf = W + O_XWF;
  float* xwb = W + O_XWB;
  float* hbuf = W + O_HBUF;
  float* cpath = W + O_CONST;
  float* spath = W + O_STRUCT;
  float* nodes = W + O_NODES;
  float* qb = W + O_QB;
  float* kb = W + O_KB;
  float* vb = W + O_VB;
  float* skb = W + O_SKB;
  float* svb = W + O_SVB;
  float* np = W + O_NP;
  float* LAl = W + O_LAL;
  float* LBl = W + O_LBL;
  float* LAb = W + O_LAB;
  float* LBb = W + O_LBB;
  u16* l1 = (u16*)(W + O_PATHS);          // link_w1[:, :3072] bf16
  u16* b1 = l1 + 2359296;                  // lab_w1[:, :3072] bf16
  u16* wbf = (u16*)(W + O_END);
  u16* cbf = wbf + B_CBF;
  u16* multibf = wbf + B_MBF;
  u16* nodesbf = wbf + B_NBF;
  u16* attoutbf = wbf + B_ABF;
  float* outlink = (float*)d_out;
  float* outlab = (float*)d_out + 18432;

  init_kernel<<<576, 256, 0, stream>>>(sentences, root, multi, multibf, bar);

  cvt_weights_kernel<<<19456, 256, 0, stream>>>(wq, wk, wv, wo, wih_f, wih_b, wr, wz,
                                                wc, wsk, wsv, wu, link_w1, lab_w1, wbf);

  {  // xw = dialog_input @ wih^T + bih via MFMA
    BJobs j{};
    j.j[0] = {wbf + B_IHF, bih_f, xwf};
    j.j[1] = {wbf + B_IHB, bih_b, xwb};
    bgemm_kernel<<<dim3(12, 18, 2), 256, 0, stream>>>(multibf, 1536, 768, 1152, j);
  }

  init_pairs_kernel<<<9216, 256, 0, stream>>>(speakers, turns, graphs, emb_speaker,
                                              emb_turn, emb_position, normal_type,
                                              cpath, spath);

  // gru (12 blocks) + hidden helpers: layer-0 lnsksv (288) + W1 conversion (84)
  mega_gru_kernel<<<384, 512, 0, stream>>>(whh_f, whh_b, bhh_f, bhh_b, xwf, xwb,
                                           hbuf, multi, multibf, bar, spath, cpath,
                                           pln_s, pln_b, cbf, bsk, bsv, skb, svb,
                                           link_w1, lab_w1, l1, b1);

  for (int layer = 0; layer < 3; ++layer) {
    const u16* nsrcbf = (layer == 0) ? (multibf + 768) : nodesbf;
    int nlda = (layer == 0) ? 1536 : 768;
    const float* nsrc = (layer == 0) ? (multi + 768) : nodes;

    if (layer > 0)
      lnsksv_kernel<<<288, 512, 0, stream>>>(spath, cpath, pln_s, pln_b, cbf, bsk,
                                             bsv, skb, svb, layer == 2 ? 1 : 0);

    {  // q, k, v via MFMA
      BJobs j{};
      j.j[0] = {wbf + B_QW, bq, qb};
      j.j[1] = {wbf + B_KW, bk, kb};
      j.j[2] = {wbf + B_VW, bv, vb};
      bgemm_kernel<<<dim3(12, 12, 3), 256, 0, stream>>>(nsrcbf, nlda, 768, 768, j);
    }

    attn_kernel<<<192, 256, 0, stream>>>(qb, kb, vb, skb, svb, edu_nums, attoutbf);

    {  // attproj -> qb via MFMA
      BJobs j{};
      j.j[0] = {wbf + B_OW, bo, qb};
      bgemm_kernel<<<dim3(12, 12, 1), 256, 0, stream>>>(attoutbf, 768, 768, 768, j);
    }

    ln_nodes_kernel<<<48, 256, 0, stream>>>(nsrc, nlda, qb, ln_s, ln_b, nodes,
                                            nodesbf);

    {  // gate pre-projections via MFMA
      BJobs j{};
      j.j[0] = {wbf + B_RA, nullptr, np + 0 * 24576};
      j.j[1] = {wbf + B_RB, nullptr, np + 1 * 24576};
      j.j[2] = {wbf + B_ZA, nullptr, np + 2 * 24576};
      j.j[3] = {wbf + B_ZB, nullptr, np + 3 * 24576};
      j.j[4] = {wbf + B_CA, nullptr, np + 4 * 24576};
      j.j[5] = {wbf + B_CB, nullptr, np + 5 * 24576};
      bgemm_kernel<<<dim3(12, 2, 6), 256, 0, stream>>>(nodesbf, 768, 768, 128, j);
    }

    gate_mfma_kernel<<<570, 256, 0, stream>>>(spath, np, cbf, br, bz, bc, bu);
  }

  {  // LA/LB via MFMA, K=1536 (l1/b1 were converted under the gru launch)
    BJobs j{};
    j.j[0] = {l1, link_b1, LAl};
    j.j[1] = {l1 + 1179648, nullptr, LBl};
    j.j[2] = {b1, lab_b1, LAb};
    j.j[3] = {b1 + 1179648, nullptr, LBb};
    bgemm_kernel<<<dim3(12, 12, 4), 256, 0, stream>>>(multibf, 1536, 1536, 768, j);
  }

  final_mfma_kernel<<<1152, 256, 0, stream>>>(spath, cbf, LAl, LBl, LAb, LBb,
                                              link_w2, lab_w2, link_b2, lab_b2,
                                              outlink, outlab);
}

// Round 11
// 953.932 us; speedup vs baseline: 1.1385x; 1.0397x over previous
//
#include <hip/hip_runtime.h>
#include <math.h>

typedef unsigned short u16;
typedef short bf16x8 __attribute__((ext_vector_type(8)));
typedef float f32x4 __attribute__((ext_vector_type(4)));

// Shapes: B=2, N=96, H=768, H2=384, P=128, HEADS=12, D=64, T=17, CIN=3200

// ---------------- workspace layout (floats, after 4KB header) ------------------
static constexpr size_t O_MULTI  = 0;                       // (192,1536)
static constexpr size_t O_XWF    = O_MULTI + 294912;        // (192,1152)
static constexpr size_t O_XWB    = O_XWF   + 221184;
static constexpr size_t O_HBUF   = O_XWB   + 221184;
static constexpr size_t O_CONST  = O_HBUF  + 3072;          // (18432,128)
static constexpr size_t O_STRUCT = O_CONST + 2359296;       // (18432,128)
static constexpr size_t O_PATHS  = O_STRUCT+ 2359296;       // l1/b1 bf16 (9.4MB)
static constexpr size_t O_NODES  = O_PATHS + 2359296;
static constexpr size_t O_QB     = O_NODES + 147456;
static constexpr size_t O_KB     = O_QB    + 147456;
static constexpr size_t O_VB     = O_KB    + 147456;
static constexpr size_t O_SKB    = O_VB    + 147456;        // (18432,64)
static constexpr size_t O_SVB    = O_SKB   + 1179648;
static constexpr size_t O_ATT    = O_SVB   + 1179648;
static constexpr size_t O_NP     = O_ATT   + 147456;        // 6 x (192,128)
static constexpr size_t O_LAL    = O_NP    + 147456;
static constexpr size_t O_LBL    = O_LAL   + 147456;
static constexpr size_t O_LAB    = O_LBL   + 147456;
static constexpr size_t O_LBB    = O_LAB   + 147456;
static constexpr size_t O_END    = O_LBB   + 147456;

// bf16 weight region WBF (u16 units), placed after O_END
static constexpr int B_QW  = 0;          // 768x768
static constexpr int B_KW  = 589824;
static constexpr int B_VW  = 1179648;
static constexpr int B_OW  = 1769472;
static constexpr int B_IHF = 2359296;    // 1152x768
static constexpr int B_IHB = 3244032;
static constexpr int B_RA  = 4128768;    // 128x768 (wr cols 0:768)
static constexpr int B_RB  = 4227072;
static constexpr int B_ZA  = 4325376;
static constexpr int B_ZB  = 4423680;
static constexpr int B_CA  = 4521984;
static constexpr int B_CB  = 4620288;
static constexpr int B_CBF = 4718592;    // 262144: wsk|wsv|wrs|wzs|wu|w1l|w1b
static constexpr int B_MBF = 4980736;    // multibf (192,1536)
static constexpr int B_NBF = 5275648;    // nodesbf (192,768)
static constexpr int B_ABF = 5423104;    // attoutbf (192,768)
static constexpr int CVT_TOT = 4980736;

// offsets inside CBF (relative)
static constexpr int C_WSK = 0;
static constexpr int C_WSV = 8192;
static constexpr int C_WRS = 16384;
static constexpr int C_WZS = 32768;
static constexpr int C_WU  = 49152;
static constexpr int C_W1L = 65536;
static constexpr int C_W1B = 163840;

__device__ __forceinline__ u16 f2bf(float f) {
  union { float f; unsigned u; } v; v.f = f;
  unsigned r = v.u + 0x7fff + ((v.u >> 16) & 1);
  return (u16)(r >> 16);
}

// ---------------- setup: weight conversion + dialog_input init + flags ---------
__global__ void setup_kernel(const float* __restrict__ wq, const float* __restrict__ wk,
                             const float* __restrict__ wv, const float* __restrict__ wo,
                             const float* __restrict__ wih_f, const float* __restrict__ wih_b,
                             const float* __restrict__ wr, const float* __restrict__ wz,
                             const float* __restrict__ wc, const float* __restrict__ wsk,
                             const float* __restrict__ wsv, const float* __restrict__ wu,
                             const float* __restrict__ link_w1, const float* __restrict__ lab_w1,
                             u16* __restrict__ wbf,
                             const float* __restrict__ sentences,
                             const float* __restrict__ root,
                             float* __restrict__ multi, u16* __restrict__ multibf,
                             int* bar) {
  int bx = blockIdx.x;
  int tid = threadIdx.x;
  if (bx < 4864) {  // cvt role: 4 elems per thread
    int g = bx * 256 + tid;
#pragma unroll
    for (int q = 0; q < 4; ++q) {
      int idx = g * 4 + q;
      float v;
      if (idx < B_IHF) {
        int which = idx / 589824, r = idx % 589824;
        const float* src = which == 0 ? wq : which == 1 ? wk : which == 2 ? wv : wo;
        v = src[r];
      } else if (idx < B_RA) {
        int r = idx - B_IHF;
        v = (r < 884736) ? wih_f[r] : wih_b[r - 884736];
      } else if (idx < B_CBF) {
        int r = idx - B_RA;
        int seg = r / 98304, qq = r % 98304;
        int row = qq / 768, c = qq % 768;
        switch (seg) {
          case 0: v = wr[(size_t)row * 1664 + c]; break;
          case 1: v = wr[(size_t)row * 1664 + 768 + c]; break;
          case 2: v = wz[(size_t)row * 1664 + c]; break;
          case 3: v = wz[(size_t)row * 1664 + 768 + c]; break;
          case 4: v = wc[(size_t)row * 1536 + c]; break;
          default: v = wc[(size_t)row * 1536 + 768 + c]; break;
        }
      } else {
        int r = idx - B_CBF;
        if (r < C_WSV) v = wsk[r];
        else if (r < C_WRS) v = wsv[r - C_WSV];
        else if (r < C_WZS) { int qr = r - C_WRS; v = wr[(size_t)(qr >> 7) * 1664 + 1536 + (qr & 127)]; }
        else if (r < C_WU)  { int qr = r - C_WZS; v = wz[(size_t)(qr >> 7) * 1664 + 1536 + (qr & 127)]; }
        else if (r < C_W1L) v = wu[r - C_WU];
        else if (r < C_W1B) { int qr = r - C_W1L; v = link_w1[(size_t)(qr >> 7) * 3200 + 3072 + (qr & 127)]; }
        else { int qr = r - C_W1B; v = lab_w1[(size_t)(qr >> 7) * 3200 + 3072 + (qr & 127)]; }
      }
      wbf[idx] = f2bf(v);
    }
    return;
  }
  int idx = (bx - 4864) * 256 + tid;
  if (idx < 12) bar[idx * 64] = 0;
  if (idx >= 2 * 96 * 768) return;
  int c = idx % 768;
  int rem = idx / 768;
  int t = rem % 96;
  int b = rem / 96;
  float v = (t == 0) ? root[c] : sentences[((size_t)(b * 95 + (t - 1))) * 768 + c];
  size_t a = ((size_t)(b * 96 + t)) * 1536 + c;
  multi[a] = v;
  multibf[a] = f2bf(v);
}

// ---------------- generic MFMA GEMM (256 thr): C = A @ W^T (+bias) -------------
struct BJob { const u16* W; const float* bias; float* C; };
struct BJobs { BJob j[6]; };

__global__ __launch_bounds__(256) void bgemm_kernel(const u16* __restrict__ A,
                                                    int lda, int K, int N, BJobs jobs) {
  BJob jb = jobs.j[blockIdx.z];
  int r0 = blockIdx.x * 16;
  int tid = threadIdx.x;
  int wave = tid >> 6, lane = tid & 63;
  int col = lane & 15, quad = lane >> 4;
  int c = blockIdx.y * 64 + wave * 16 + col;
  const u16* arow = A + (size_t)(r0 + col) * lda + quad * 8;
  const u16* brow = jb.W + (size_t)c * K + quad * 8;
  f32x4 acc = {0.f, 0.f, 0.f, 0.f};
  for (int k = 0; k < K; k += 32) {
    bf16x8 af = *(const bf16x8*)(arow + k);
    bf16x8 bf = *(const bf16x8*)(brow + k);
    acc = __builtin_amdgcn_mfma_f32_16x16x32_bf16(af, bf, acc, 0, 0, 0);
  }
  float bv = jb.bias ? jb.bias[c] : 0.f;
#pragma unroll
  for (int r = 0; r < 4; ++r)
    jb.C[(size_t)(r0 + quad * 4 + r) * N + c] = acc[r] + bv;
}

// ---------------- 512-thread bgemm body (128 cols/block) -----------------------
__device__ __forceinline__ void bgemm512(const u16* __restrict__ A, int lda, int K,
                                         int N, const u16* __restrict__ Wt,
                                         const float* __restrict__ bias,
                                         float* __restrict__ C, int rowblk,
                                         int colblk, int tid) {
  int wave = tid >> 6, lane = tid & 63;
  int col = lane & 15, quad = lane >> 4;
  int c = colblk * 128 + wave * 16 + col;
  int r0 = rowblk * 16;
  const u16* arow = A + (size_t)(r0 + col) * lda + quad * 8;
  const u16* brow = Wt + (size_t)c * K + quad * 8;
  f32x4 acc = {0.f, 0.f, 0.f, 0.f};
  for (int k = 0; k < K; k += 32) {
    bf16x8 af = *(const bf16x8*)(arow + k);
    bf16x8 bf = *(const bf16x8*)(brow + k);
    acc = __builtin_amdgcn_mfma_f32_16x16x32_bf16(af, bf, acc, 0, 0, 0);
  }
  float bv = bias ? bias[c] : 0.f;
#pragma unroll
  for (int r = 0; r < 4; ++r)
    C[(size_t)(r0 + quad * 4 + r) * N + c] = acc[r] + bv;
}

// ---------------- sk/sv MFMA tail (shared by lnsksv bodies) --------------------
__device__ __forceinline__ void sksv_tail(int tid, int p0, const u16* plds,
                                          const u16* __restrict__ cbf,
                                          const float* __restrict__ bsk,
                                          const float* __restrict__ bsv,
                                          float* __restrict__ skb,
                                          float* __restrict__ svb) {
  int wave = tid >> 6, lane = tid & 63;
  int mat = wave >> 2, rowg = wave & 3;
  const u16* wb = cbf + (mat ? C_WSV : C_WSK);
  const float* bias = mat ? bsv : bsk;
  float* out = mat ? svb : skb;
  int col = lane & 15, quad = lane >> 4;
  bf16x8 afrag[4];
  const u16* arow = plds + (rowg * 16 + col) * 136 + quad * 8;
#pragma unroll
  for (int c = 0; c < 4; ++c) afrag[c] = *(const bf16x8*)(arow + 32 * c);
#pragma unroll
  for (int nt = 0; nt < 4; ++nt) {
    f32x4 acc = {0.f, 0.f, 0.f, 0.f};
    const u16* brow = wb + (size_t)(nt * 16 + col) * 128 + quad * 8;
#pragma unroll
    for (int c = 0; c < 4; ++c)
      acc = __builtin_amdgcn_mfma_f32_16x16x32_bf16(afrag[c], *(const bf16x8*)(brow + 32 * c), acc, 0, 0, 0);
    int o = nt * 16 + col;
    float bv = bias[o];
#pragma unroll
    for (int r = 0; r < 4; ++r)
      out[(size_t)(p0 + rowg * 16 + quad * 4 + r) * 64 + o] = acc[r] + bv;
  }
}

// ------- fused symmetrize + LN(struct+const) + sk/sv MFMA (layers 1/2) ---------
__device__ __forceinline__ void lnsksv_body(int blk, int tid,
                                            float* __restrict__ spath,
                                            const float* __restrict__ cpath,
                                            const float* __restrict__ pln_s,
                                            const float* __restrict__ pln_b,
                                            const u16* __restrict__ cbf,
                                            const float* __restrict__ bsk,
                                            const float* __restrict__ bsv,
                                            float* __restrict__ skb,
                                            float* __restrict__ svb,
                                            int store_upper, u16* plds) {
  int p0 = blk * 64;
  int wave = tid >> 6, lane = tid & 63;
  float pls0 = pln_s[lane], pls1 = pln_s[lane + 64];
  float plb0 = pln_b[lane], plb1 = pln_b[lane + 64];
#pragma unroll
  for (int pp = 0; pp < 8; ++pp) {
    int pl = wave * 8 + pp;
    int p = p0 + pl;
    int j = p % 96;
    int rem = p / 96;
    int i = rem % 96;
    int b = rem / 96;
    size_t self = (size_t)p * 128;
    const float* src = (i < j) ? (spath + ((size_t)((b * 96 + j) * 96 + i)) * 128)
                               : (spath + self);
    float v0 = src[lane], v1 = src[lane + 64];
    if (store_upper && i < j) {
      spath[self + lane] = v0;
      spath[self + lane + 64] = v1;
    }
    float x0 = v0 + cpath[self + lane];
    float x1 = v1 + cpath[self + lane + 64];
    float s = x0 + x1;
    for (int off = 32; off; off >>= 1) s += __shfl_xor(s, off, 64);
    float mean = s * (1.f / 128.f);
    float d0 = x0 - mean, d1 = x1 - mean;
    float vs = d0 * d0 + d1 * d1;
    for (int off = 32; off; off >>= 1) vs += __shfl_xor(vs, off, 64);
    float rstd = rsqrtf(vs * (1.f / 128.f) + 1e-5f);
    plds[pl * 136 + lane] = f2bf(d0 * rstd * pls0 + plb0);
    plds[pl * 136 + lane + 64] = f2bf(d1 * rstd * pls1 + plb1);
  }
  __syncthreads();
  sksv_tail(tid, p0, plds, cbf, bsk, bsv, skb, svb);
}

// ------- layer-0 body: inline cpath/spath init + LN + sk/sv --------------------
__device__ __forceinline__ void lnsksv0_body(int blk, int tid,
                                             const int* __restrict__ speakers,
                                             const int* __restrict__ turns,
                                             const int* __restrict__ graphs,
                                             const float* __restrict__ emb_speaker,
                                             const float* __restrict__ emb_turn,
                                             const float* __restrict__ emb_position,
                                             const float* __restrict__ normal_type,
                                             float* __restrict__ cpath,
                                             float* __restrict__ spath,
                                             const float* __restrict__ pln_s,
                                             const float* __restrict__ pln_b,
                                             const u16* __restrict__ cbf,
                                             const float* __restrict__ bsk,
                                             const float* __restrict__ bsv,
                                             float* __restrict__ skb,
                                             float* __restrict__ svb, u16* plds) {
  int p0 = blk * 64;
  int wave = tid >> 6, lane = tid & 63;
  float pls0 = pln_s[lane], pls1 = pln_s[lane + 64];
  float plb0 = pln_b[lane], plb1 = pln_b[lane + 64];
#pragma unroll
  for (int pp = 0; pp < 8; ++pp) {
    int pl = wave * 8 + pp;
    int p = p0 + pl;
    int j = p % 96;
    int rem = p / 96;
    int i = rem % 96;
    int b = rem / 96;
    int sp = speakers[p], tn = turns[p];
    int g2 = graphs[p] + graphs[(b * 96 + j) * 96 + i];
    int d = min(max(j - i, -11), 11) + 11;
    float cv0 = (lane < 32) ? emb_speaker[sp * 32 + lane] : emb_turn[tn * 32 + lane - 32];
    float cv1 = emb_position[d * 64 + lane];
    float s0 = (g2 == 0) ? 0.f : normal_type[(g2 - 1) * 128 + lane];
    float s1 = (g2 == 0) ? 0.f : normal_type[(g2 - 1) * 128 + 64 + lane];
    size_t self = (size_t)p * 128;
    cpath[self + lane] = cv0;
    cpath[self + lane + 64] = cv1;
    spath[self + lane] = s0;      // symmetric init: covers both triangles
    spath[self + lane + 64] = s1;
    float x0 = s0 + cv0;
    float x1 = s1 + cv1;
    float s = x0 + x1;
    for (int off = 32; off; off >>= 1) s += __shfl_xor(s, off, 64);
    float mean = s * (1.f / 128.f);
    float d0 = x0 - mean, d1 = x1 - mean;
    float vs = d0 * d0 + d1 * d1;
    for (int off = 32; off; off >>= 1) vs += __shfl_xor(vs, off, 64);
    float rstd = rsqrtf(vs * (1.f / 128.f) + 1e-5f);
    plds[pl * 136 + lane] = f2bf(d0 * rstd * pls0 + plb0);
    plds[pl * 136 + lane + 64] = f2bf(d1 * rstd * pls1 + plb1);
  }
  __syncthreads();
  sksv_tail(tid, p0, plds, cbf, bsk, bsv, skb, svb);
}

// ---------------- mega kernel: gru (12 blocks) + hidden helpers ----------------
__global__ __launch_bounds__(512) void mega_gru_kernel(
    const float* __restrict__ whh_f, const float* __restrict__ whh_b,
    const float* __restrict__ bhh_f, const float* __restrict__ bhh_b,
    const float* __restrict__ xwf, const float* __restrict__ xwb,
    float* hbuf, float* multi, u16* multibf, int* bar,
    const int* __restrict__ speakers, const int* __restrict__ turns,
    const int* __restrict__ graphs, const float* __restrict__ emb_speaker,
    const float* __restrict__ emb_turn, const float* __restrict__ emb_position,
    const float* __restrict__ normal_type, float* __restrict__ cpath,
    float* __restrict__ spath,
    const float* __restrict__ pln_s, const float* __restrict__ pln_b,
    const u16* __restrict__ cbf, const float* __restrict__ bsk,
    const float* __restrict__ bsv, float* __restrict__ skb,
    float* __restrict__ svb, const float* __restrict__ link_w1,
    const float* __restrict__ lab_w1, u16* __restrict__ l1, u16* __restrict__ b1) {
  __shared__ float hlds[768];
  __shared__ float part[3][64][2][17];
  __shared__ u16 plds[64 * 136];
  int bx = blockIdx.x;
  int tid = threadIdx.x;

  if (bx >= 300) {  // W1 conversion helpers
    for (int idx = (bx - 300) * 512 + tid; idx < 2359296; idx += 84 * 512) {
      int half = idx / 1179648;
      int r = idx % 1179648;
      int row = r / 1536, c = r % 1536;
      size_t src = (size_t)row * 3200 + half * 1536 + c;
      l1[idx] = f2bf(link_w1[src]);
      b1[idx] = f2bf(lab_w1[src]);
    }
    return;
  }
  if (bx >= 12) {  // layer-0 init+lnsksv helpers
    lnsksv0_body(bx - 12, tid, speakers, turns, graphs, emb_speaker, emb_turn,
                 emb_position, normal_type, cpath, spath, pln_s, pln_b, cbf, bsk,
                 bsv, skb, svb, plds);
    return;
  }

  // ---- gru role ----
  int dir = bx / 6;
  int sub = bx % 6;
  const float* whh = dir ? whh_b : whh_f;
  const float* bhh = dir ? bhh_b : bhh_f;
  const float* xw = dir ? xwb : xwf;
  float* hb = hbuf + (size_t)dir * 1536;
  int* flags = bar + dir * 6 * 64;

  int ks = tid >> 5;
  int ug = tid & 31;
  int hv0 = ug * 2;

  float4 wreg[6][6];
#pragma unroll
  for (int d = 0; d < 2; ++d)
#pragma unroll
    for (int g = 0; g < 3; ++g) {
      const float* wrow = whh + (size_t)(g * 384 + sub * 64 + hv0 + d) * 384 + ks * 24;
#pragma unroll
      for (int m = 0; m < 6; ++m) wreg[d * 3 + g][m] = *(const float4*)(wrow + m * 4);
    }
  float bh0 = 0.f, bh1 = 0.f, bh2 = 0.f;
  int hvC = 0, bsel = 0;
  if (tid < 128) {
    hvC = sub * 64 + (tid >> 1);
    bsel = tid & 1;
    bh0 = bhh[hvC];
    bh1 = bhh[384 + hvC];
    bh2 = bhh[768 + hvC];
  }

  for (int s = 0; s < 96; ++s) {
    int t = dir ? (95 - s) : s;
    float xr = 0.f, xz = 0.f, xn = 0.f;
    if (tid < 128) {
      const float* xrow = xw + (size_t)(bsel * 96 + t) * 1152;
      xr = xrow[hvC]; xz = xrow[384 + hvC]; xn = xrow[768 + hvC];
    }
    if (s == 0) {
      __syncthreads();
      for (int k = tid; k < 768; k += 512) hlds[k] = 0.f;
    } else {
      if (tid < 6) {
        while (__hip_atomic_load(&flags[tid * 64], __ATOMIC_RELAXED,
                                 __HIP_MEMORY_SCOPE_AGENT) < s)
          __builtin_amdgcn_s_sleep(1);
      }
      __syncthreads();
      const float* hsrc = hb + ((s - 1) & 1) * 768;
      for (int k = tid; k < 768; k += 512)
        hlds[k] = __hip_atomic_load(&hsrc[k], __ATOMIC_RELAXED, __HIP_MEMORY_SCOPE_AGENT);
    }
    __syncthreads();

    float acc[6][2];
#pragma unroll
    for (int b = 0; b < 2; ++b) {
      float4 h4[6];
      const float* hp = hlds + b * 384 + ks * 24;
#pragma unroll
      for (int m = 0; m < 6; ++m) h4[m] = *(const float4*)(hp + m * 4);
#pragma unroll
      for (int u = 0; u < 6; ++u) {
        float ssum = 0.f;
#pragma unroll
        for (int m = 0; m < 6; ++m) {
          float4 w = wreg[u][m];
          ssum += w.x * h4[m].x + w.y * h4[m].y + w.z * h4[m].z + w.w * h4[m].w;
        }
        acc[u][b] = ssum;
      }
    }
#pragma unroll
    for (int d = 0; d < 2; ++d)
#pragma unroll
      for (int g = 0; g < 3; ++g) {
        part[g][hv0 + d][0][ks] = acc[d * 3 + g][0];
        part[g][hv0 + d][1][ks] = acc[d * 3 + g][1];
      }
    __syncthreads();

    float hn = 0.f;
    if (tid < 128) {
      int hv = tid >> 1;
      float gr = bh0, gz = bh1, gn = bh2;
#pragma unroll
      for (int q = 0; q < 16; ++q) {
        gr += part[0][hv][bsel][q];
        gz += part[1][hv][bsel][q];
        gn += part[2][hv][bsel][q];
      }
      float r = 1.f / (1.f + expf(-(xr + gr)));
      float z = 1.f / (1.f + expf(-(xz + gz)));
      float n = tanhf(xn + r * gn);
      float hp = hlds[bsel * 384 + hvC];
      hn = (1.f - z) * n + z * hp;
      __hip_atomic_store(&hb[(s & 1) * 768 + bsel * 384 + hvC], hn, __ATOMIC_RELAXED,
                         __HIP_MEMORY_SCOPE_AGENT);
    }
    asm volatile("s_waitcnt vmcnt(0)" ::: "memory");
    __syncthreads();
    if (tid == 0)
      __hip_atomic_store(&flags[sub * 64], s + 1, __ATOMIC_RELAXED,
                         __HIP_MEMORY_SCOPE_AGENT);
    if (tid < 128) {
      size_t a = ((size_t)(bsel * 96 + t)) * 1536 + 768 + dir * 384 + hvC;
      multi[a] = hn;
      multibf[a] = f2bf(hn);
    }
  }
}

// ---------------- merged layer-boundary kernel ---------------------------------
// blocks [0,288): lnsksv; [288,504): qkv (512-thr bgemm, 128 cols);
// [504,792) when has_lab: LA/LB K=1536 bgemm.
__global__ __launch_bounds__(512) void layerA_kernel(
    float* __restrict__ spath, const float* __restrict__ cpath,
    const float* __restrict__ pln_s, const float* __restrict__ pln_b,
    const u16* __restrict__ cbf, const float* __restrict__ bsk,
    const float* __restrict__ bsv, float* __restrict__ skb,
    float* __restrict__ svb, int store_upper,
    const u16* __restrict__ nodesbf, const u16* __restrict__ wbf,
    const float* __restrict__ bq, const float* __restrict__ bk,
    const float* __restrict__ bv, float* __restrict__ qb, float* __restrict__ kb,
    float* __restrict__ vb, const u16* __restrict__ multibf,
    const u16* __restrict__ l1, const u16* __restrict__ b1,
    const float* __restrict__ link_b1, const float* __restrict__ lab_b1,
    float* __restrict__ LAl, float* __restrict__ LBl, float* __restrict__ LAb,
    float* __restrict__ LBb) {
  __shared__ u16 plds[64 * 136];
  int bx = blockIdx.x;
  int tid = threadIdx.x;
  if (bx < 288) {
    lnsksv_body(bx, tid, spath, cpath, pln_s, pln_b, cbf, bsk, bsv, skb, svb,
                store_upper, plds);
    return;
  }
  int bxl = bx - 288;
  if (bxl < 216) {  // qkv: 3 jobs x 12 rowblk x 6 colblk
    int job = bxl / 72, rem = bxl % 72;
    int rowblk = rem % 12, colblk = rem / 12;
    const u16* Wt = wbf + (job == 0 ? B_QW : job == 1 ? B_KW : B_VW);
    const float* bias = job == 0 ? bq : job == 1 ? bk : bv;
    float* C = job == 0 ? qb : job == 1 ? kb : vb;
    bgemm512(nodesbf, 768, 768, 768, Wt, bias, C, rowblk, colblk, tid);
    return;
  }
  bxl -= 216;  // LA/LB: 4 jobs x 12 rowblk x 6 colblk
  int job = bxl / 72, rem = bxl % 72;
  int rowblk = rem % 12, colblk = rem / 12;
  const u16* Wt = job == 0 ? l1 : job == 1 ? l1 + 1179648 : job == 2 ? b1
                                                                     : b1 + 1179648;
  const float* bias = job == 0 ? link_b1 : job == 2 ? lab_b1 : nullptr;
  float* C = job == 0 ? LAl : job == 1 ? LBl : job == 2 ? LAb : LBb;
  bgemm512(multibf, 1536, 1536, 768, Wt, bias, C, rowblk, colblk, tid);
}

// ---------------- fused attention per (b,i), bf16 output ------------------------
__global__ __launch_bounds__(256) void attn_kernel(const float* __restrict__ qb,
                                                   const float* __restrict__ kb,
                                                   const float* __restrict__ vb,
                                                   const float* __restrict__ skb,
                                                   const float* __restrict__ svb,
                                                   const int* __restrict__ edu_nums,
                                                   u16* __restrict__ attout) {
  int bi = blockIdx.x;
  int b = bi / 96;
  __shared__ float qrow[768];
  __shared__ float sc[12][100];
  int tid = threadIdx.x;
  for (int k = tid; k < 768; k += 256) qrow[k] = qb[(size_t)bi * 768 + k];
  int edun = edu_nums[b];
  __syncthreads();
  for (int task = tid; task < 12 * 96; task += 256) {
    int h = task / 96, j = task % 96;
    const float* krow = kb + ((size_t)(b * 96 + j)) * 768 + h * 64;
    const float* skrow = skb + ((size_t)(bi * 96 + j)) * 64;
    float s = 0.f;
    for (int d4 = 0; d4 < 64; d4 += 4) {
      float4 qv = *(const float4*)(qrow + h * 64 + d4);
      float4 kv = *(const float4*)(krow + d4);
      float4 sv = *(const float4*)(skrow + d4);
      s += qv.x * (kv.x + sv.x) + qv.y * (kv.y + sv.y) + qv.z * (kv.z + sv.z) +
           qv.w * (kv.w + sv.w);
    }
    s *= 0.125f;
    if (j >= edun) s -= 1e9f;
    sc[h][j] = s;
  }
  __syncthreads();
  if (tid < 192) {  // 16 threads per head
    int h = tid >> 4, s5 = tid & 15;
    float m = -3.4e38f;
    for (int j = s5; j < 96; j += 16) m = fmaxf(m, sc[h][j]);
    m = fmaxf(m, __shfl_xor(m, 1, 64));
    m = fmaxf(m, __shfl_xor(m, 2, 64));
    m = fmaxf(m, __shfl_xor(m, 4, 64));
    m = fmaxf(m, __shfl_xor(m, 8, 64));
    float sum = 0.f;
    for (int j = s5; j < 96; j += 16) {
      float e = expf(sc[h][j] - m);
      sc[h][j] = e;
      sum += e;
    }
    sum += __shfl_xor(sum, 1, 64);
    sum += __shfl_xor(sum, 2, 64);
    sum += __shfl_xor(sum, 4, 64);
    sum += __shfl_xor(sum, 8, 64);
    float r = 1.f / sum;
    for (int j = s5; j < 96; j += 16) sc[h][j] *= r;
  }
  __syncthreads();
  for (int o = tid; o < 768; o += 256) {
    int h = o >> 6, d = o & 63;
    float acc = 0.f;
    const float* vcol = vb + (size_t)(b * 96) * 768 + o;
    const float* svcol = svb + ((size_t)(bi * 96)) * 64 + d;
    for (int j = 0; j < 96; ++j) acc += sc[h][j] * (vcol[j * 768] + svcol[j * 64]);
    attout[(size_t)bi * 768 + o] = f2bf(acc);
  }
}

// ---------------- nodes = LN(src + relu(proj)), fp32 + bf16 out -----------------
__global__ __launch_bounds__(256) void ln_nodes_kernel(const float* __restrict__ src,
                                                       int lda,
                                                       const float* __restrict__ proj,
                                                       const float* __restrict__ ln_s,
                                                       const float* __restrict__ ln_b,
                                                       float* __restrict__ nodes,
                                                       u16* __restrict__ nodesbf) {
  int row = blockIdx.x * 4 + (threadIdx.x >> 6);
  int lane = threadIdx.x & 63;
  float x[12];
  float s = 0.f;
#pragma unroll
  for (int m = 0; m < 12; ++m) {
    int e = lane + m * 64;
    float v = src[(size_t)row * lda + e] + fmaxf(proj[(size_t)row * 768 + e], 0.f);
    x[m] = v;
    s += v;
  }
  for (int off = 32; off; off >>= 1) s += __shfl_xor(s, off, 64);
  float mean = s * (1.f / 768.f);
  float vs = 0.f;
#pragma unroll
  for (int m = 0; m < 12; ++m) {
    float d = x[m] - mean;
    x[m] = d;
    vs += d * d;
  }
  for (int off = 32; off; off >>= 1) vs += __shfl_xor(vs, off, 64);
  float rstd = rsqrtf(vs * (1.f / 768.f) + 1e-5f);
#pragma unroll
  for (int m = 0; m < 12; ++m) {
    int e = lane + m * 64;
    float v = x[m] * rstd * ln_s[e] + ln_b[e];
    nodes[(size_t)row * 768 + e] = v;
    nodesbf[(size_t)row * 768 + e] = f2bf(v);
  }
}

// ---------------- pairwise gate update via MFMA (tril pairs) --------------------
__global__ __launch_bounds__(256) void gate_mfma_kernel(float* __restrict__ spath,
                                                        const float* __restrict__ np,
                                                        const u16* __restrict__ cbf,
                                                        const float* __restrict__ br,
                                                        const float* __restrict__ bz,
                                                        const float* __restrict__ bc,
                                                        const float* __restrict__ bu) {
  __shared__ int addrs[16], npi[16], npj[16];
  int tid = threadIdx.x;
  if (tid < 16) {
    int pid = blockIdx.x * 16 + tid;
    int b = pid / 4560;
    int t = pid % 4560;
    int i = (int)((sqrtf(8.f * (float)t + 1.f) + 1.f) * 0.5f);
    while (i * (i - 1) / 2 > t) --i;
    while ((i + 1) * i / 2 <= t) ++i;
    int j = t - i * (i - 1) / 2;
    addrs[tid] = ((b * 96 + i) * 96 + j) * 128;
    npi[tid] = (b * 96 + i) * 128;
    npj[tid] = (b * 96 + j) * 128;
  }
  __syncthreads();

  int wave = tid >> 6, lane = tid & 63;
  int col = lane & 15, quad = lane >> 4;

  bf16x8 afrag[4];
  {
    const float* arow = spath + (size_t)addrs[col] + quad * 8;
#pragma unroll
    for (int c = 0; c < 4; ++c) {
      bf16x8 f;
#pragma unroll
      for (int q = 0; q < 8; ++q) f[q] = (short)f2bf(arow[32 * c + q]);
      afrag[c] = f;
    }
  }

  const u16* wrs = cbf + C_WRS;
  const u16* wzs = cbf + C_WZS;
  const u16* wu = cbf + C_WU;

  f32x4 cr[2], cz[2], cu[2];
#pragma unroll
  for (int ct = 0; ct < 2; ++ct) {
    cr[ct] = {0.f, 0.f, 0.f, 0.f};
    cz[ct] = {0.f, 0.f, 0.f, 0.f};
    cu[ct] = {0.f, 0.f, 0.f, 0.f};
    int o0 = wave * 32 + ct * 16;
    const u16* br_ = wrs + (size_t)(o0 + col) * 128 + quad * 8;
    const u16* bz_ = wzs + (size_t)(o0 + col) * 128 + quad * 8;
    const u16* bu_ = wu + (size_t)(o0 + col) * 128 + quad * 8;
#pragma unroll
    for (int c = 0; c < 4; ++c) {
      cr[ct] = __builtin_amdgcn_mfma_f32_16x16x32_bf16(afrag[c], *(const bf16x8*)(br_ + 32 * c), cr[ct], 0, 0, 0);
      cz[ct] = __builtin_amdgcn_mfma_f32_16x16x32_bf16(afrag[c], *(const bf16x8*)(bz_ + 32 * c), cz[ct], 0, 0, 0);
      cu[ct] = __builtin_amdgcn_mfma_f32_16x16x32_bf16(afrag[c], *(const bf16x8*)(bu_ + 32 * c), cu[ct], 0, 0, 0);
    }
  }

#pragma unroll
  for (int ct = 0; ct < 2; ++ct) {
    int o = wave * 32 + ct * 16 + col;
    float brv = br[o], bzv = bz[o], bcv = bc[o], buv = bu[o];
#pragma unroll
    for (int r4 = 0; r4 < 4; ++r4) {
      int m = quad * 4 + r4;
      int sa = addrs[m] + o;
      float so = spath[sa];
      float nra = np[0 * 24576 + npj[m] + o];
      float nrb = np[1 * 24576 + npi[m] + o];
      float nza = np[2 * 24576 + npj[m] + o];
      float nzb = np[3 * 24576 + npi[m] + o];
      float nca = np[4 * 24576 + npj[m] + o];
      float ncb = np[5 * 24576 + npi[m] + o];
      float r = 1.f / (1.f + expf(-(cr[ct][r4] + nra + nrb + brv)));
      float z = 1.f / (1.f + expf(-(cz[ct][r4] + nza + nzb + bzv)));
      float u = tanhf(nca + ncb + bcv + r * (cu[ct][r4] + buv));
      spath[sa] = z * so + (1.f - z) * u;
    }
  }
}

// ---------------- final fused link/label head (MFMA, converts spath inline) ----
__global__ __launch_bounds__(256) void final_mfma_kernel(
    const float* __restrict__ spath, const u16* __restrict__ cbf,
    const float* __restrict__ LAl, const float* __restrict__ LBl,
    const float* __restrict__ LAb, const float* __restrict__ LBb,
    const float* __restrict__ w2l, const float* __restrict__ w2b,
    const float* __restrict__ b2l, const float* __restrict__ b2b,
    float* __restrict__ outlink, float* __restrict__ outlab) {
  const u16* w1l = cbf + C_W1L;
  const u16* w1b = cbf + C_W1B;
  int p0 = blockIdx.x * 16;
  int j0 = p0 % 96;
  int rem = p0 / 96;
  int i = rem % 96;
  int b = rem / 96;
  int tid = threadIdx.x;
  int wave = tid >> 6;
  int lane = tid & 63;
  int col = lane & 15;
  int quad = lane >> 4;

  __shared__ float redl[4][16];
  __shared__ float red[4][16][17];

  bf16x8 afrag[4];
  {
    const float* arow = spath + (size_t)(p0 + col) * 128 + quad * 8;
#pragma unroll
    for (int c = 0; c < 4; ++c) {
      bf16x8 f;
#pragma unroll
      for (int q = 0; q < 8; ++q) f[q] = (short)f2bf(arow[32 * c + q]);
      afrag[c] = f;
    }
  }

  float lacc[4] = {0.f, 0.f, 0.f, 0.f};
  float at[4][17];
#pragma unroll
  for (int r = 0; r < 4; ++r)
#pragma unroll
    for (int t = 0; t < 17; ++t) at[r][t] = 0.f;

  const float* LBl_row = LBl + (size_t)(b * 96 + i) * 768;
  const float* LBb_row = LBb + (size_t)(b * 96 + i) * 768;

  for (int nt = wave; nt < 48; nt += 4) {
    int o0 = nt * 16;
    f32x4 c = {0.f, 0.f, 0.f, 0.f};
    const u16* brow = w1l + (size_t)(o0 + col) * 128 + quad * 8;
#pragma unroll
    for (int cc = 0; cc < 4; ++cc) {
      bf16x8 bf = *(const bf16x8*)(brow + 32 * cc);
      c = __builtin_amdgcn_mfma_f32_16x16x32_bf16(afrag[cc], bf, c, 0, 0, 0);
    }
    int o = o0 + col;
    float lb = LBl_row[o];
    float w2 = w2l[o];
#pragma unroll
    for (int r = 0; r < 4; ++r) {
      int m = quad * 4 + r;
      float la = LAl[(size_t)(b * 96 + j0 + m) * 768 + o];
      float h = tanhf(c[r] + la + lb);
      lacc[r] += h * w2;
    }
  }

  for (int nt = wave; nt < 48; nt += 4) {
    int o0 = nt * 16;
    f32x4 c = {0.f, 0.f, 0.f, 0.f};
    const u16* brow = w1b + (size_t)(o0 + col) * 128 + quad * 8;
#pragma unroll
    for (int cc = 0; cc < 4; ++cc) {
      bf16x8 bf = *(const bf16x8*)(brow + 32 * cc);
      c = __builtin_amdgcn_mfma_f32_16x16x32_bf16(afrag[cc], bf, c, 0, 0, 0);
    }
    int o = o0 + col;
    float lb = LBb_row[o];
#pragma unroll
    for (int r = 0; r < 4; ++r) {
      int m = quad * 4 + r;
      float la = LAb[(size_t)(b * 96 + j0 + m) * 768 + o];
      float h = tanhf(c[r] + la + lb);
#pragma unroll
      for (int t = 0; t < 17; ++t) at[r][t] += h * w2b[t * 768 + o];
    }
  }

#pragma unroll
  for (int r = 0; r < 4; ++r) {
    lacc[r] += __shfl_xor(lacc[r], 1, 64);
    lacc[r] += __shfl_xor(lacc[r], 2, 64);
    lacc[r] += __shfl_xor(lacc[r], 4, 64);
    lacc[r] += __shfl_xor(lacc[r], 8, 64);
#pragma unroll
    for (int t = 0; t < 17; ++t) {
      at[r][t] += __shfl_xor(at[r][t], 1, 64);
      at[r][t] += __shfl_xor(at[r][t], 2, 64);
      at[r][t] += __shfl_xor(at[r][t], 4, 64);
      at[r][t] += __shfl_xor(at[r][t], 8, 64);
    }
  }
  if (col == 0) {
#pragma unroll
    for (int r = 0; r < 4; ++r) {
      int m = quad * 4 + r;
      redl[wave][m] = lacc[r];
#pragma unroll
      for (int t = 0; t < 17; ++t) red[wave][m][t] = at[r][t];
    }
  }
  __syncthreads();
  if (tid < 16) {
    float s = redl[0][tid] + redl[1][tid] + redl[2][tid] + redl[3][tid];
    outlink[(size_t)((b * 96 + i) * 96) + j0 + tid] = s + b2l[0];
  }
  for (int task = tid; task < 16 * 17; task += 256) {
    int m = task / 17, t = task % 17;
    float s = red[0][m][t] + red[1][m][t] + red[2][m][t] + red[3][m][t];
    outlab[((size_t)((b * 96 + i) * 96) + j0 + m) * 17 + t] = s + b2b[t];
  }
}

// ================================ launcher ======================================
extern "C" void kernel_launch(void* const* d_in, const int* in_sizes, int n_in,
                              void* d_out, int out_size, void* d_ws, size_t ws_size,
                              hipStream_t stream) {
  (void)in_sizes; (void)n_in; (void)out_size; (void)ws_size;
  const float* sentences = (const float*)d_in[0];
  const int* speakers = (const int*)d_in[1];
  const int* turns = (const int*)d_in[2];
  const int* graphs = (const int*)d_in[3];
  const int* edu_nums = (const int*)d_in[4];
  const float* root = (const float*)d_in[5];
  const float* wih_f = (const float*)d_in[6];
  const float* whh_f = (const float*)d_in[7];
  const float* bih_f = (const float*)d_in[8];
  const float* bhh_f = (const float*)d_in[9];
  const float* wih_b = (const float*)d_in[10];
  const float* whh_b = (const float*)d_in[11];
  const float* bih_b = (const float*)d_in[12];
  const float* bhh_b = (const float*)d_in[13];
  const float* emb_speaker = (const float*)d_in[14];
  const float* emb_turn = (const float*)d_in[15];
  const float* emb_position = (const float*)d_in[16];
  const float* normal_type = (const float*)d_in[17];
  const float* wr = (const float*)d_in[18];
  const float* br = (const float*)d_in[19];
  const float* wz = (const float*)d_in[20];
  const float* bz = (const float*)d_in[21];
  const float* wc = (const float*)d_in[22];
  const float* bc = (const float*)d_in[23];
  const float* wu = (const float*)d_in[24];
  const float* bu = (const float*)d_in[25];
  const float* wq = (const float*)d_in[26];
  const float* wk = (const float*)d_in[27];
  const float* wv = (const float*)d_in[28];
  const float* wo = (const float*)d_in[29];
  const float* bq = (const float*)d_in[30];
  const float* bk = (const float*)d_in[31];
  const float* bv = (const float*)d_in[32];
  const float* bo = (const float*)d_in[33];
  const float* wsk = (const float*)d_in[34];
  const float* bsk = (const float*)d_in[35];
  const float* wsv = (const float*)d_in[36];
  const float* bsv = (const float*)d_in[37];
  const float* ln_s = (const float*)d_in[38];
  const float* ln_b = (const float*)d_in[39];
  const float* pln_s = (const float*)d_in[40];
  const float* pln_b = (const float*)d_in[41];
  const float* link_w1 = (const float*)d_in[42];
  const float* link_b1 = (const float*)d_in[43];
  const float* link_w2 = (const float*)d_in[44];
  const float* link_b2 = (const float*)d_in[45];
  const float* lab_w1 = (const float*)d_in[46];
  const float* lab_b1 = (const float*)d_in[47];
  const float* lab_w2 = (const float*)d_in[48];
  const float* lab_b2 = (const float*)d_in[49];

  int* bar = (int*)d_ws;
  float* W = (float*)((char*)d_ws + 4096);
  float* multi = W + O_MULTI;
  float* xwf = W + O_XWF;
  float* xwb = W + O_XWB;
  float* hbuf = W + O_HBUF;
  float* cpath = W + O_CONST;
  float* spath = W + O_STRUCT;
  float* nodes = W + O_NODES;
  float* qb = W + O_QB;
  float* kb = W + O_KB;
  float* vb = W + O_VB;
  float* skb = W + O_SKB;
  float* svb = W + O_SVB;
  float* np = W + O_NP;
  float* LAl = W + O_LAL;
  float* LBl = W + O_LBL;
  float* LAb = W + O_LAB;
  float* LBb = W + O_LBB;
  u16* l1 = (u16*)(W + O_PATHS);
  u16* b1 = l1 + 2359296;
  u16* wbf = (u16*)(W + O_END);
  u16* cbf = wbf + B_CBF;
  u16* multibf = wbf + B_MBF;
  u16* nodesbf = wbf + B_NBF;
  u16* attoutbf = wbf + B_ABF;
  float* outlink = (float*)d_out;
  float* outlab = (float*)d_out + 18432;

  setup_kernel<<<5440, 256, 0, stream>>>(wq, wk, wv, wo, wih_f, wih_b, wr, wz, wc,
                                         wsk, wsv, wu, link_w1, lab_w1, wbf,
                                         sentences, root, multi, multibf, bar);

  {  // xw = dialog_input @ wih^T + bih via MFMA
    BJobs j{};
    j.j[0] = {wbf + B_IHF, bih_f, xwf};
    j.j[1] = {wbf + B_IHB, bih_b, xwb};
    bgemm_kernel<<<dim3(12, 18, 2), 256, 0, stream>>>(multibf, 1536, 768, 1152, j);
  }

  // gru (12) + L0 init+lnsksv (288) + W1 cvt (84)
  mega_gru_kernel<<<384, 512, 0, stream>>>(whh_f, whh_b, bhh_f, bhh_b, xwf, xwb,
                                           hbuf, multi, multibf, bar, speakers,
                                           turns, graphs, emb_speaker, emb_turn,
                                           emb_position, normal_type, cpath, spath,
                                           pln_s, pln_b, cbf, bsk, bsv, skb, svb,
                                           link_w1, lab_w1, l1, b1);

  for (int layer = 0; layer < 3; ++layer) {
    const u16* nsrcbf = (layer == 0) ? (multibf + 768) : nodesbf;
    int nlda = (layer == 0) ? 1536 : 768;
    const float* nsrc = (layer == 0) ? (multi + 768) : nodes;

    if (layer == 0) {
      BJobs j{};
      j.j[0] = {wbf + B_QW, bq, qb};
      j.j[1] = {wbf + B_KW, bk, kb};
      j.j[2] = {wbf + B_VW, bv, vb};
      bgemm_kernel<<<dim3(12, 12, 3), 256, 0, stream>>>(nsrcbf, nlda, 768, 768, j);
    } else {
      int has_lab = (layer == 1);
      layerA_kernel<<<288 + 216 + (has_lab ? 288 : 0), 512, 0, stream>>>(
          spath, cpath, pln_s, pln_b, cbf, bsk, bsv, skb, svb,
          (layer == 2) ? 1 : 0, nodesbf, wbf, bq, bk, bv, qb, kb, vb, multibf, l1,
          b1, link_b1, lab_b1, LAl, LBl, LAb, LBb);
    }

    attn_kernel<<<192, 256, 0, stream>>>(qb, kb, vb, skb, svb, edu_nums, attoutbf);

    {  // attproj -> qb via MFMA
      BJobs j{};
      j.j[0] = {wbf + B_OW, bo, qb};
      bgemm_kernel<<<dim3(12, 12, 1), 256, 0, stream>>>(attoutbf, 768, 768, 768, j);
    }

    ln_nodes_kernel<<<48, 256, 0, stream>>>(nsrc, nlda, qb, ln_s, ln_b, nodes,
                                            nodesbf);

    {  // gate pre-projections via MFMA
      BJobs j{};
      j.j[0] = {wbf + B_RA, nullptr, np + 0 * 24576};
      j.j[1] = {wbf + B_RB, nullptr, np + 1 * 24576};
      j.j[2] = {wbf + B_ZA, nullptr, np + 2 * 24576};
      j.j[3] = {wbf + B_ZB, nullptr, np + 3 * 24576};
      j.j[4] = {wbf + B_CA, nullptr, np + 4 * 24576};
      j.j[5] = {wbf + B_CB, nullptr, np + 5 * 24576};
      bgemm_kernel<<<dim3(12, 2, 6), 256, 0, stream>>>(nodesbf, 768, 768, 128, j);
    }

    gate_mfma_kernel<<<570, 256, 0, stream>>>(spath, np, cbf, br, bz, bc, bu);
  }

  final_mfma_kernel<<<1152, 256, 0, stream>>>(spath, cbf, LAl, LBl, LAb, LBb,
                                              link_w2, lab_w2, link_b2, lab_b2,
                                              outlink, outlab);
}